// Round 10
// baseline (395.979 us; speedup 1.0000x reference)
//
#include <hip/hip_runtime.h>
#include <math.h>

constexpr int HD = 128;   // hidden dim
constexpr int FD = 64;    // input feature dim
constexpr int PCH = 32;   // pooling chunks per graph
constexpr int BKT_SHIFT = 8;           // 256 nodes per bucket
constexpr int EPB = 2048;              // edges per block in bucket passes
constexpr float FP8_SCALE = 16.f;      // pre-scale before e4m3 quantization
constexpr float FP8_INV_SCALE = 1.f / 16.f;

typedef unsigned int uint;
typedef unsigned short ushort;
typedef unsigned char uchar;

using bf16x8 = __attribute__((ext_vector_type(8))) short;   // 4 VGPRs
using f32x4  = __attribute__((ext_vector_type(4))) float;

#if defined(__has_builtin)
#if __has_builtin(__builtin_amdgcn_cvt_pk_f32_fp8) && __has_builtin(__builtin_amdgcn_cvt_pk_fp8_f32)
#define HW_FP8 1
#endif
#endif

static __device__ inline ushort f2bf(float f) {   // round-to-nearest-even bf16
  uint u = __float_as_uint(f);
  return (ushort)((u + 0x7fffu + ((u >> 16) & 1u)) >> 16);
}
static __device__ inline float bf2f(ushort b) {
  return __uint_as_float((uint)b << 16);
}
static __device__ inline uint pack2bf(float a, float b) {
  return (uint)f2bf(a) | ((uint)f2bf(b) << 16);
}

// ---- fp8 e4m3 (OCP) helpers: HW path + fallback ----
static __device__ inline uchar enc_fp8_byte(float f) {
#ifdef HW_FP8
  return (uchar)(__builtin_amdgcn_cvt_pk_fp8_f32(f, f, 0, false) & 0xff);
#else
  float a = fabsf(f);
  uint s = (f < 0.f) ? 0x80u : 0u;
  if (!(a > 0.f)) return (uchar)s;
  a = fminf(a, 448.f);
  uint b = __float_as_uint(a);
  int e = (int)(b >> 23) - 127;
  if (e < -6) {                       // denormal domain: multiples of 2^-9
    int q = (int)rintf(a * 512.f);
    if (q <= 0) return (uchar)s;
    if (q >= 8) return (uchar)(s | 0x08u);
    return (uchar)(s | (uint)q);
  }
  uint r = b + 0x7ffffu + ((b >> 20) & 1u);   // RTN-even at mantissa bit 20
  uint m = (r >> 20) & 7u;
  int ee = (int)(r >> 23) - 127 + 7;
  if (ee <= 0) return (uchar)(s | 0x08u);
  if (ee > 15) return (uchar)(s | 0x7eu);
  return (uchar)(s | ((uint)ee << 3) | m);
#endif
}

static __device__ inline float dec_fp8_byte(uint em_s) {   // fallback scalar decode
  uint s = (em_s & 0x80u) << 24;
  uint em = em_s & 0x7fu;
  float v;
  if (em < 8) v = (float)em * (1.f / 512.f);
  else v = __uint_as_float((em + (120u << 3)) << 20);
  return __uint_as_float(__float_as_uint(v) | s);
}

static __device__ inline void dec_fp8x4(uint u, float* dst) {
#ifdef HW_FP8
  auto a = __builtin_amdgcn_cvt_pk_f32_fp8((int)u, false);
  auto b = __builtin_amdgcn_cvt_pk_f32_fp8((int)u, true);
  dst[0] = a[0]; dst[1] = a[1]; dst[2] = b[0]; dst[3] = b[1];
#else
  dst[0] = dec_fp8_byte(u & 0xffu);
  dst[1] = dec_fp8_byte((u >> 8) & 0xffu);
  dst[2] = dec_fp8_byte((u >> 16) & 0xffu);
  dst[3] = dec_fp8_byte(u >> 24);
#endif
}

// ---------------- utility ----------------
__global__ void zero_int_kernel(int* __restrict__ p, int n) {
  int i = blockIdx.x * blockDim.x + threadIdx.x;
  if (i < n) p[i] = 0;
}

// ---------------- bucketed CSR build (also produces offs, dinv) ----------------
__global__ __launch_bounds__(256) void bucket_count_kernel(const int* __restrict__ dst,
    int* __restrict__ bucket_count, int e, int nbk) {
  __shared__ int hist[512];
  int t = threadIdx.x;
  for (int i = t; i < nbk; i += 256) hist[i] = 0;
  __syncthreads();
  int lo = blockIdx.x * EPB;
  int hi = lo + EPB; if (hi > e) hi = e;
  for (int i = lo + t; i < hi; i += 256) atomicAdd(&hist[dst[i] >> BKT_SHIFT], 1);
  __syncthreads();
  for (int i = t; i < nbk; i += 256) {
    int c = hist[i];
    if (c) atomicAdd(&bucket_count[i], c);
  }
}

__global__ __launch_bounds__(512) void bucket_scan_kernel(const int* __restrict__ bucket_count,
    int* __restrict__ bucket_base, int* __restrict__ bucket_cursor, int nbk) {
  __shared__ int sh[512];
  int t = threadIdx.x;
  int v = (t < nbk) ? bucket_count[t] : 0;
  sh[t] = v;
  __syncthreads();
  for (int d = 1; d < 512; d <<= 1) {
    int u = (t >= d) ? sh[t - d] : 0;
    __syncthreads();
    sh[t] += u;
    __syncthreads();
  }
  if (t < nbk) {
    int ex = sh[t] - v;
    bucket_base[t] = ex;
    bucket_cursor[t] = ex;
  }
  if (t == 511) bucket_base[nbk] = sh[511];
}

// pairs packed: (src << 8) | (dst & 255); src < 2^17, bucket-local dst < 256
__global__ __launch_bounds__(256) void bucket_fill_kernel(const int* __restrict__ src,
    const int* __restrict__ dst, int* __restrict__ bucket_cursor,
    uint* __restrict__ pairs, int e, int nbk) {
  __shared__ int hist[512];
  int t = threadIdx.x;
  for (int i = t; i < nbk; i += 256) hist[i] = 0;
  __syncthreads();
  int lo = blockIdx.x * EPB;
  int hi = lo + EPB; if (hi > e) hi = e;
  for (int i = lo + t; i < hi; i += 256) atomicAdd(&hist[dst[i] >> BKT_SHIFT], 1);
  __syncthreads();
  for (int i = t; i < nbk; i += 256) {
    int c = hist[i];
    hist[i] = c ? atomicAdd(&bucket_cursor[i], c) : 0;   // hist now = write cursor
  }
  __syncthreads();
  for (int i = lo + t; i < hi; i += 256) {
    int s = src[i], d = dst[i];
    int pos = atomicAdd(&hist[d >> BKT_SHIFT], 1);
    pairs[pos] = ((uint)s << 8) | (uint)(d & 255);
  }
}

// one block per bucket: count per-node in LDS, scan -> offs & dinv, then scatter
__global__ __launch_bounds__(256) void bucket_scatter_kernel(const uint* __restrict__ pairs,
    const int* __restrict__ bucket_base, int* __restrict__ offs,
    float* __restrict__ dinv, int* __restrict__ csr_src, int n, int nbk) {
  __shared__ int cnt[256];
  __shared__ int pre[256];
  int b = blockIdx.x, t = threadIdx.x;
  int node0 = b << BKT_SHIFT;
  bool valid_node = (node0 + t) < n;
  cnt[t] = 0;
  __syncthreads();
  int lo = bucket_base[b], hi = bucket_base[b + 1];
  for (int i = lo + t; i < hi; i += 256)
    atomicAdd(&cnt[pairs[i] & 255u], 1);
  __syncthreads();
  int v = cnt[t];
  pre[t] = v;
  __syncthreads();
  for (int d = 1; d < 256; d <<= 1) {
    int u = (t >= d) ? pre[t - d] : 0;
    __syncthreads();
    pre[t] += u;
    __syncthreads();
  }
  int off = lo + pre[t] - v;   // exclusive prefix within bucket + bucket base
  if (valid_node) {
    offs[node0 + t] = off;
    dinv[node0 + t] = rsqrtf((float)(v + 1));   // +1: self-loop
  }
  __syncthreads();
  cnt[t] = off;   // reuse as cursor
  __syncthreads();
  for (int i = lo + t; i < hi; i += 256) {
    uint pp = pairs[i];
    int pos = atomicAdd(&cnt[pp & 255u], 1);
    csr_src[pos] = (int)(pp >> 8);
  }
  if (b == 0 && t == 0) offs[n] = bucket_base[nbk];
}

// ---------------- all weight transposes fused: wt[c][k] = bf16(W[k][c]) ------------
__global__ void convert_all_wt_kernel(const float* __restrict__ enc_w1,
    const float* __restrict__ enc_w2, const float* __restrict__ gcn_w,
    ushort* __restrict__ wt_e1, ushort* __restrict__ wt_e2, ushort* __restrict__ wt_g,
    int L) {
  const int S0 = 128 * FD, S1 = 128 * HD;
  int i = blockIdx.x * 256 + threadIdx.x;
  if (i < S0) {
    int c = i / FD, k = i - c * FD;
    wt_e1[i] = f2bf(enc_w1[k * 128 + c]);
  } else if (i < S0 + S1) {
    int j = i - S0;
    int c = j / HD, k = j - c * HD;
    wt_e2[j] = f2bf(enc_w2[k * 128 + c]);
  } else if (i < S0 + S1 + L * S1) {
    int j = i - S0 - S1;
    int l = j / S1, jj = j - l * S1;
    int c = jj / HD, k = jj - c * HD;
    wt_g[(size_t)l * S1 + jj] = f2bf(gcn_w[(size_t)l * HD * HD + k * 128 + c]);
  }
}

// ---------------- MFMA GEMM: C[M x 128] = A[M x K] @ W[K x 128] ----------------
// FP8OUT: write fp8(e4m3) of (o * dinv[row] * 16) -- GCN message rows.
// else:   write bf16 (+bias)(+relu).
template<typename TA, int K, bool BIAS, bool RELU, bool FP8OUT>
__global__ __launch_bounds__(256) void mfma_gemm_kernel(const TA* __restrict__ A,
    const ushort* __restrict__ Wt, const float* __restrict__ bias,
    void* __restrict__ Cout, const float* __restrict__ dinv, int M) {
  __shared__ ushort As[64 * K];
  __shared__ ushort Ws[128 * K];
  const int tid = threadIdx.x;
  const int r0 = blockIdx.x * 64;

  if constexpr (sizeof(TA) == 4) {
    constexpr int C4 = K / 4;
    const float4* A4 = (const float4*)A;
    #pragma unroll
    for (int i = tid; i < 64 * C4; i += 256) {
      int r = i / C4, c4 = i - r * C4;
      int row = r0 + r;
      float4 v = make_float4(0.f, 0.f, 0.f, 0.f);
      if (row < M) v = A4[(size_t)row * C4 + c4];
      ushort4 u;
      u.x = f2bf(v.x); u.y = f2bf(v.y); u.z = f2bf(v.z); u.w = f2bf(v.w);
      int elem = (r * K + c4 * 4) ^ ((r & 7) << 3);
      *(ushort4*)&As[elem] = u;
    }
  } else {
    constexpr int C8 = K / 8;
    const uint4* A4 = (const uint4*)A;
    #pragma unroll
    for (int i = tid; i < 64 * C8; i += 256) {
      int r = i / C8, c8 = i - r * C8;
      int row = r0 + r;
      uint4 v = make_uint4(0u, 0u, 0u, 0u);
      if (row < M) v = A4[(size_t)row * C8 + c8];
      int elem = (r * K + c8 * 8) ^ ((r & 7) << 3);
      *(uint4*)&As[elem] = v;
    }
  }
  {
    constexpr int C8 = K / 8;
    const uint4* W4 = (const uint4*)Wt;
    #pragma unroll
    for (int i = tid; i < 128 * C8; i += 256) {
      int c = i / C8, k8 = i - c * C8;
      uint4 v = W4[i];
      int elem = (c * K + k8 * 8) ^ ((c & 7) << 3);
      *(uint4*)&Ws[elem] = v;
    }
  }
  __syncthreads();

  const int l = tid & 63;
  const int wid = tid >> 6;
  const int lr = l & 15;       // fragment row/col within 16
  const int lk = l >> 4;       // k sub-block 0..3
  const int wr = wid * 16;     // wave's row base in tile
  f32x4 acc[8];
  #pragma unroll
  for (int cb = 0; cb < 8; ++cb) acc[cb] = (f32x4){0.f, 0.f, 0.f, 0.f};

  #pragma unroll
  for (int kc = 0; kc < K / 32; ++kc) {
    int ar = wr + lr;
    bf16x8 af = *(const bf16x8*)&As[(ar * K + kc * 32 + lk * 8) ^ ((ar & 7) << 3)];
    #pragma unroll
    for (int cb = 0; cb < 8; ++cb) {
      int col = cb * 16 + lr;
      bf16x8 bfr = *(const bf16x8*)&Ws[(col * K + kc * 32 + lk * 8) ^ ((col & 7) << 3)];
      acc[cb] = __builtin_amdgcn_mfma_f32_16x16x32_bf16(af, bfr, acc[cb], 0, 0, 0);
    }
  }

  if constexpr (FP8OUT) {
    uchar* C8p = (uchar*)Cout;
    float dv[4];
    #pragma unroll
    for (int j = 0; j < 4; ++j) {
      int row = r0 + wr + lk * 4 + j;
      dv[j] = (row < M) ? dinv[row] * FP8_SCALE : 0.f;
    }
    #pragma unroll
    for (int cb = 0; cb < 8; ++cb) {
      int col = cb * 16 + lr;
      #pragma unroll
      for (int j = 0; j < 4; ++j) {
        int row = r0 + wr + lk * 4 + j;
        if (row < M) {
          C8p[(size_t)row * 128 + col] = enc_fp8_byte(acc[cb][j] * dv[j]);
        }
      }
    }
  } else {
    ushort* Cb = (ushort*)Cout;
    #pragma unroll
    for (int cb = 0; cb < 8; ++cb) {
      int col = cb * 16 + lr;
      float bb = BIAS ? bias[col] : 0.f;
      #pragma unroll
      for (int j = 0; j < 4; ++j) {
        int row = r0 + wr + lk * 4 + j;
        if (row < M) {
          float o = acc[cb][j] + bb;
          if (RELU) o = fmaxf(o, 0.f);
          Cb[(size_t)row * 128 + col] = f2bf(o);
        }
      }
    }
  }
}

// ---------------- GCN aggregation + residual update ----------------
// xws rows are fp8: xws[i] = xw[i]*dinv[i]*16. Update:
//   x[i] (bf16) += relu( (dinv[i]/16) * (sum_{src} xws[src] + xws[i]) + bias )
// One wave per node; 8 edge-groups x 8 lanes (uint4 = 16 fp8 per lane);
// 2-deep unroll -> 16 rows in flight, 8 edges per gather instruction (1KB).
__global__ __launch_bounds__(256) void agg_update_kernel(
    const uchar* __restrict__ xws, ushort* __restrict__ x,
    const int* __restrict__ csr_src, const int* __restrict__ offs,
    const float* __restrict__ dinv, const float* __restrict__ bias, int n) {
  int node = blockIdx.x * 4 + (threadIdx.x >> 6);
  if (node >= n) return;
  int lane = threadIdx.x & 63;
  int grp = lane >> 3;       // edge group 0..7
  int cl = lane & 7;         // row chunk: dims 16*cl .. 16*cl+15
  const uint4* xw4 = (const uint4*)xws;   // row = 8 uint4 (128 fp8)
  float acc[16];
  #pragma unroll
  for (int k = 0; k < 16; ++k) acc[k] = 0.f;

  auto add_row = [&](uint4 v) {
    float f[4];
    dec_fp8x4(v.x, f);
    acc[0] += f[0]; acc[1] += f[1]; acc[2] += f[2]; acc[3] += f[3];
    dec_fp8x4(v.y, f);
    acc[4] += f[0]; acc[5] += f[1]; acc[6] += f[2]; acc[7] += f[3];
    dec_fp8x4(v.z, f);
    acc[8] += f[0]; acc[9] += f[1]; acc[10] += f[2]; acc[11] += f[3];
    dec_fp8x4(v.w, f);
    acc[12] += f[0]; acc[13] += f[1]; acc[14] += f[2]; acc[15] += f[3];
  };

  int beg = offs[node], end = offs[node + 1];
  int j = beg + grp;
  for (; j + 8 < end; j += 16) {
    int s0 = csr_src[j];
    int s1 = csr_src[j + 8];
    uint4 v0 = xw4[(size_t)s0 * 8 + cl];
    uint4 v1 = xw4[(size_t)s1 * 8 + cl];
    add_row(v0); add_row(v1);
  }
  if (j < end) {
    uint4 v0 = xw4[(size_t)csr_src[j] * 8 + cl];
    add_row(v0);
  }
  if (grp == 0) {   // self-loop term
    uint4 vi = xw4[(size_t)node * 8 + cl];
    add_row(vi);
  }
  #pragma unroll
  for (int k = 0; k < 16; ++k) {
    acc[k] += __shfl_xor(acc[k], 8);
    acc[k] += __shfl_xor(acc[k], 16);
    acc[k] += __shfl_xor(acc[k], 32);
  }
  if (grp == 0) {
    float di = dinv[node] * FP8_INV_SCALE;
    const float4* b4 = (const float4*)bias;
    uint4* xv4 = (uint4*)x;
    size_t xi = (size_t)node * 16 + cl * 2;   // two uint4 of bf16 per lane
    uint4 xa = xv4[xi], xb = xv4[xi + 1];
    uint xu[8] = {xa.x, xa.y, xa.z, xa.w, xb.x, xb.y, xb.z, xb.w};
    float o[16];
    #pragma unroll
    for (int q = 0; q < 4; ++q) {
      float4 bb = b4[cl * 4 + q];
      float bv[4] = {bb.x, bb.y, bb.z, bb.w};
      #pragma unroll
      for (int r = 0; r < 2; ++r) {
        int k = q * 4 + r * 2;
        uint u = xu[q * 2 + r];   // wrong pairing guard: recompute below
      }
    }
    // dims 16cl+d, d=0..15; bf16 word d -> uint xu[d>>1] half (d&1)
    #pragma unroll
    for (int d = 0; d < 16; d += 2) {
      uint u = xu[d >> 1];
      float lo = __uint_as_float(u << 16);
      float hi = __uint_as_float(u & 0xffff0000u);
      const float* bbp = (const float*)b4;   // bias as flat floats
      float b0 = bbp[16 * cl + d];
      float b1 = bbp[16 * cl + d + 1];
      o[d]     = fmaxf(fmaf(acc[d],     di, b0), 0.f) + lo;
      o[d + 1] = fmaxf(fmaf(acc[d + 1], di, b1), 0.f) + hi;
    }
    uint4 oa, ob;
    oa.x = pack2bf(o[0], o[1]);   oa.y = pack2bf(o[2], o[3]);
    oa.z = pack2bf(o[4], o[5]);   oa.w = pack2bf(o[6], o[7]);
    ob.x = pack2bf(o[8], o[9]);   ob.y = pack2bf(o[10], o[11]);
    ob.z = pack2bf(o[12], o[13]); ob.w = pack2bf(o[14], o[15]);
    xv4[xi] = oa;
    xv4[xi + 1] = ob;
  }
}

// ---------------- graph boundaries from sorted batch ----------------
__global__ void bounds_kernel(const int* __restrict__ batch, int* __restrict__ startg,
                              int n, int ng) {
  int i = blockIdx.x * blockDim.x + threadIdx.x;
  if (i > n) return;
  int bi = (i < n) ? batch[i] : ng;
  int bp = (i == 0) ? -1 : batch[i - 1];
  for (int g = bp + 1; g <= bi && g <= ng; ++g) startg[g] = i;
}

// ---------------- per-graph mean/max pooling: partial stage, vectorized ----------------
// 256 threads: 16 row-groups x 16 col-groups (uint4 = 8 bf16 per thread).
__global__ __launch_bounds__(256) void pool_partial_kernel(const ushort* __restrict__ x,
    const int* __restrict__ startg, float* __restrict__ psum, float* __restrict__ pmax) {
  __shared__ float ssum[16][128];
  __shared__ float smax[16][128];
  int g = blockIdx.x / PCH, ch = blockIdx.x % PCH;
  int t = threadIdx.x;
  int rg = t >> 4, cg = t & 15;
  int s0 = startg[g], s1 = startg[g + 1];
  int cnt = s1 - s0;
  int len = (cnt + PCH - 1) / PCH;
  int lo = s0 + ch * len;
  int hi = lo + len; if (hi > s1) hi = s1;
  float sum[8], mx[8];
  #pragma unroll
  for (int k = 0; k < 8; ++k) { sum[k] = 0.f; mx[k] = -INFINITY; }
  const uint4* x4 = (const uint4*)x;
  for (int r = lo + rg; r < hi; r += 16) {
    uint4 v = x4[(size_t)r * 16 + cg];
    uint uu[4] = {v.x, v.y, v.z, v.w};
    #pragma unroll
    for (int q = 0; q < 4; ++q) {
      float a = __uint_as_float(uu[q] << 16);
      float b = __uint_as_float(uu[q] & 0xffff0000u);
      sum[2 * q] += a;     mx[2 * q]     = fmaxf(mx[2 * q], a);
      sum[2 * q + 1] += b; mx[2 * q + 1] = fmaxf(mx[2 * q + 1], b);
    }
  }
  #pragma unroll
  for (int k = 0; k < 8; ++k) {
    ssum[rg][cg * 8 + k] = sum[k];
    smax[rg][cg * 8 + k] = mx[k];
  }
  __syncthreads();
  #pragma unroll
  for (int d = 8; d > 0; d >>= 1) {
    if (rg < d) {
      #pragma unroll
      for (int k = 0; k < 8; ++k) {
        int c = cg * 8 + k;
        ssum[rg][c] += ssum[rg + d][c];
        smax[rg][c] = fmaxf(smax[rg][c], smax[rg + d][c]);
      }
    }
    __syncthreads();
  }
  if (rg == 0) {
    #pragma unroll
    for (int k = 0; k < 8; ++k) {
      int c = cg * 8 + k;
      psum[(size_t)blockIdx.x * HD + c] = ssum[0][c];
      pmax[(size_t)blockIdx.x * HD + c] = smax[0][c];
    }
  }
}

// ---------------- pool-final + decoder + value heads (one block per graph) ----------
__global__ __launch_bounds__(128) void heads_kernel(
    const float* __restrict__ psum, const float* __restrict__ pmax,
    const int* __restrict__ startg,
    const float* __restrict__ dw1, const float* __restrict__ db1,
    const float* __restrict__ dw2, const float* __restrict__ db2,
    const float* __restrict__ dw3, const float* __restrict__ db3,
    const float* __restrict__ vw1, const float* __restrict__ vb1,
    const float* __restrict__ vw2, const float* __restrict__ vb2,
    float* __restrict__ out, int ng) {
  __shared__ float rep[256];
  __shared__ float h1[128];
  __shared__ float h2[64];
  __shared__ float v1[128];
  int g = blockIdx.x, t = threadIdx.x;
  {
    float sum = 0.f, mx = -INFINITY;
    #pragma unroll
    for (int ch = 0; ch < PCH; ++ch) {
      sum += psum[(size_t)(g * PCH + ch) * HD + t];
      mx = fmaxf(mx, pmax[(size_t)(g * PCH + ch) * HD + t]);
    }
    int cnt = startg[g + 1] - startg[g];
    float denom = (float)(cnt > 0 ? cnt : 1);
    rep[t] = sum / denom;
    rep[128 + t] = mx;
  }
  __syncthreads();
  float a = db1[t], b = vb1[t];
  for (int k = 0; k < 256; ++k) {
    float rv = rep[k];
    a = fmaf(rv, dw1[k * 128 + t], a);
    b = fmaf(rv, vw1[k * 128 + t], b);
  }
  h1[t] = fmaxf(a, 0.f);
  v1[t] = fmaxf(b, 0.f);
  __syncthreads();
  if (t < 64) {
    float c = db2[t];
    for (int k = 0; k < 128; ++k) c = fmaf(h1[k], dw2[k * 64 + t], c);
    h2[t] = fmaxf(c, 0.f);
  }
  __syncthreads();
  if (t == 0) {
    float l0 = db3[0], l2 = db3[2];
    for (int k = 0; k < 64; ++k) {
      l0 = fmaf(h2[k], dw3[k * 3 + 0], l0);
      l2 = fmaf(h2[k], dw3[k * 3 + 2], l2);
    }
    out[g] = 1.f / (1.f + expf(-l0));          // adaptation_prob
    out[ng + g] = 1.0f;                        // softmax over 1 element == 1
    out[2 * ng + g] = 1.f / (1.f + expf(-l2)); // urgency_score
    float v = vb2[0];
    for (int k = 0; k < 128; ++k) v = fmaf(v1[k], vw2[k], v);
    out[3 * ng + g] = v;                       // value_estimate
  }
}

// ---------------- launch ----------------
extern "C" void kernel_launch(void* const* d_in, const int* in_sizes, int n_in,
                              void* d_out, int out_size, void* d_ws, size_t ws_size,
                              hipStream_t stream) {
  const float* nf     = (const float*)d_in[0];
  const int*   ei     = (const int*)d_in[1];
  const int*   batch  = (const int*)d_in[2];
  const float* enc_w1 = (const float*)d_in[3];
  const float* enc_b1 = (const float*)d_in[4];
  const float* enc_w2 = (const float*)d_in[5];
  const float* enc_b2 = (const float*)d_in[6];
  const float* gcn_w  = (const float*)d_in[7];
  const float* gcn_b  = (const float*)d_in[8];
  const float* dec_w1 = (const float*)d_in[9];
  const float* dec_b1 = (const float*)d_in[10];
  const float* dec_w2 = (const float*)d_in[11];
  const float* dec_b2 = (const float*)d_in[12];
  const float* dec_w3 = (const float*)d_in[13];
  const float* dec_b3 = (const float*)d_in[14];
  const float* val_w1 = (const float*)d_in[15];
  const float* val_b1 = (const float*)d_in[16];
  const float* val_w2 = (const float*)d_in[17];
  const float* val_b2 = (const float*)d_in[18];
  float* out = (float*)d_out;

  const int n = in_sizes[0] / FD;           // 100000
  const int e = in_sizes[1] / 2;            // 1600000
  const int L = in_sizes[7] / (HD * HD);    // 3
  const int G = out_size / 4;               // 64

  // workspace carve
  char* p = (char*)d_ws;
  auto carve = [&](size_t bytes) {
    void* r = (void*)p;
    p += (bytes + 255) & ~(size_t)255;
    return r;
  };
  ushort* x       = (ushort*)carve((size_t)n * HD * 2);    // bf16 x
  ushort* xwb     = (ushort*)carve((size_t)n * HD * 2);    // bf16 encoder tmp
  uchar*  xw8     = (uchar*)carve((size_t)n * HD);         // fp8 message rows
  float*  dinv    = (float*)carve((size_t)n * 4);
  int*    offs    = (int*)carve((size_t)(n + 1) * 4);
  int*    csr_src = (int*)carve((size_t)e * 4);
  int*    startg  = (int*)carve((size_t)(G + 1) * 4);
  float*  psum    = (float*)carve((size_t)G * PCH * HD * 4);
  float*  pmax    = (float*)carve((size_t)G * PCH * HD * 4);
  const int nbk   = (n + (1 << BKT_SHIFT) - 1) >> BKT_SHIFT;   // 391 buckets
  int*    bucket_count  = (int*)carve((size_t)nbk * 4);
  int*    bucket_base   = (int*)carve((size_t)(nbk + 1) * 4);
  int*    bucket_cursor = (int*)carve((size_t)nbk * 4);
  ushort* wt_e1   = (ushort*)carve((size_t)128 * FD * 2);      // enc_w1^T bf16
  ushort* wt_e2   = (ushort*)carve((size_t)128 * HD * 2);      // enc_w2^T bf16
  ushort* wt_g    = (ushort*)carve((size_t)3 * 128 * HD * 2);  // gcn_w^T bf16
  // pairs aliases xwb: CSR build completes before enc1 writes xwb (stream-ordered)
  uint*   pairs   = (uint*)xwb;

  const int gemm_grid = (n + 63) / 64;
  const int ebk_grid = (e + EPB - 1) / EPB;

  // ---- graph structure (before encoder so pairs can alias xwb) ----
  zero_int_kernel<<<(nbk + 255) / 256, 256, 0, stream>>>(bucket_count, nbk);
  bucket_count_kernel<<<ebk_grid, 256, 0, stream>>>(ei + e, bucket_count, e, nbk);
  bucket_scan_kernel<<<1, 512, 0, stream>>>(bucket_count, bucket_base, bucket_cursor, nbk);
  bucket_fill_kernel<<<ebk_grid, 256, 0, stream>>>(ei, ei + e, bucket_cursor, pairs, e, nbk);
  bucket_scatter_kernel<<<nbk, 256, 0, stream>>>(pairs, bucket_base, offs, dinv, csr_src, n, nbk);

  // ---- weight transposes (one kernel) ----
  {
    int tot = 128 * FD + 128 * HD + L * 128 * HD;
    convert_all_wt_kernel<<<(tot + 255) / 256, 256, 0, stream>>>(
        enc_w1, enc_w2, gcn_w, wt_e1, wt_e2, wt_g, L);
  }

  // ---- encoder: nf @ w1 -> relu (bf16), @ w2 -> x (bf16) ----
  mfma_gemm_kernel<float, FD, true, true, false><<<gemm_grid, 256, 0, stream>>>(
      nf, wt_e1, enc_b1, xwb, nullptr, n);
  mfma_gemm_kernel<ushort, HD, true, false, false><<<gemm_grid, 256, 0, stream>>>(
      xwb, wt_e2, enc_b2, x, nullptr, n);

  // ---- GCN layers: GEMM writes fp8 rows pre-scaled by dinv*16 ----
  for (int l = 0; l < L; ++l) {
    mfma_gemm_kernel<ushort, HD, false, false, true><<<gemm_grid, 256, 0, stream>>>(
        x, wt_g + (size_t)l * 128 * HD, nullptr, xw8, dinv, n);
    agg_update_kernel<<<(n + 3) / 4, 256, 0, stream>>>(
        xw8, x, csr_src, offs, dinv, gcn_b + (size_t)l * HD, n);
  }

  // ---- pooling + heads ----
  bounds_kernel<<<(n + 1 + 255) / 256, 256, 0, stream>>>(batch, startg, n, G);
  pool_partial_kernel<<<G * PCH, 256, 0, stream>>>(x, startg, psum, pmax);
  heads_kernel<<<G, 128, 0, stream>>>(psum, pmax, startg,
      dec_w1, dec_b1, dec_w2, dec_b2, dec_w3, dec_b3,
      val_w1, val_b1, val_w2, val_b2, out, G);
}

// Round 11
// 373.645 us; speedup vs baseline: 1.0598x; 1.0598x over previous
//
#include <hip/hip_runtime.h>
#include <math.h>

constexpr int HD = 128;   // hidden dim
constexpr int FD = 64;    // input feature dim
constexpr int PCH = 32;   // pooling chunks per graph
constexpr int BKT_SHIFT = 8;           // 256 nodes per bucket
constexpr int EPB = 2048;              // edges per block in bucket passes
constexpr float FP8_SCALE = 16.f;      // pre-scale before e4m3 quantization
constexpr float FP8_INV_SCALE = 1.f / 16.f;

typedef unsigned int uint;
typedef unsigned short ushort;
typedef unsigned char uchar;

using bf16x8 = __attribute__((ext_vector_type(8))) short;   // 4 VGPRs
using f32x4  = __attribute__((ext_vector_type(4))) float;

#if defined(__has_builtin)
#if __has_builtin(__builtin_amdgcn_cvt_pk_f32_fp8) && __has_builtin(__builtin_amdgcn_cvt_pk_fp8_f32)
#define HW_FP8 1
#endif
#endif

static __device__ inline ushort f2bf(float f) {   // round-to-nearest-even bf16
  uint u = __float_as_uint(f);
  return (ushort)((u + 0x7fffu + ((u >> 16) & 1u)) >> 16);
}
static __device__ inline float bf2f(ushort b) {
  return __uint_as_float((uint)b << 16);
}
static __device__ inline uint pack2bf(float a, float b) {
  return (uint)f2bf(a) | ((uint)f2bf(b) << 16);
}

// ---- fp8 e4m3 (OCP) helpers: HW path + fallback ----
static __device__ inline uchar enc_fp8_byte(float f) {
#ifdef HW_FP8
  return (uchar)(__builtin_amdgcn_cvt_pk_fp8_f32(f, f, 0, false) & 0xff);
#else
  float a = fabsf(f);
  uint s = (f < 0.f) ? 0x80u : 0u;
  if (!(a > 0.f)) return (uchar)s;
  a = fminf(a, 448.f);
  uint b = __float_as_uint(a);
  int e = (int)(b >> 23) - 127;
  if (e < -6) {                       // denormal domain: multiples of 2^-9
    int q = (int)rintf(a * 512.f);
    if (q <= 0) return (uchar)s;
    if (q >= 8) return (uchar)(s | 0x08u);
    return (uchar)(s | (uint)q);
  }
  uint r = b + 0x7ffffu + ((b >> 20) & 1u);   // RTN-even at mantissa bit 20
  uint m = (r >> 20) & 7u;
  int ee = (int)(r >> 23) - 127 + 7;
  if (ee <= 0) return (uchar)(s | 0x08u);
  if (ee > 15) return (uchar)(s | 0x7eu);
  return (uchar)(s | ((uint)ee << 3) | m);
#endif
}

static __device__ inline float dec_fp8_byte(uint em_s) {   // fallback scalar decode
  uint s = (em_s & 0x80u) << 24;
  uint em = em_s & 0x7fu;
  float v;
  if (em < 8) v = (float)em * (1.f / 512.f);
  else v = __uint_as_float((em + (120u << 3)) << 20);
  return __uint_as_float(__float_as_uint(v) | s);
}

static __device__ inline void dec_fp8x4(uint u, float* dst) {
#ifdef HW_FP8
  auto a = __builtin_amdgcn_cvt_pk_f32_fp8((int)u, false);
  auto b = __builtin_amdgcn_cvt_pk_f32_fp8((int)u, true);
  dst[0] = a[0]; dst[1] = a[1]; dst[2] = b[0]; dst[3] = b[1];
#else
  dst[0] = dec_fp8_byte(u & 0xffu);
  dst[1] = dec_fp8_byte((u >> 8) & 0xffu);
  dst[2] = dec_fp8_byte((u >> 16) & 0xffu);
  dst[3] = dec_fp8_byte(u >> 24);
#endif
}

// ---------------- utility ----------------
__global__ void zero_int_kernel(int* __restrict__ p, int n) {
  int i = blockIdx.x * blockDim.x + threadIdx.x;
  if (i < n) p[i] = 0;
}

// ---------------- bucketed CSR build (also produces offs, dinv) ----------------
__global__ __launch_bounds__(256) void bucket_count_kernel(const int* __restrict__ dst,
    int* __restrict__ bucket_count, int e, int nbk) {
  __shared__ int hist[512];
  int t = threadIdx.x;
  for (int i = t; i < nbk; i += 256) hist[i] = 0;
  __syncthreads();
  int lo = blockIdx.x * EPB;
  int hi = lo + EPB; if (hi > e) hi = e;
  for (int i = lo + t; i < hi; i += 256) atomicAdd(&hist[dst[i] >> BKT_SHIFT], 1);
  __syncthreads();
  for (int i = t; i < nbk; i += 256) {
    int c = hist[i];
    if (c) atomicAdd(&bucket_count[i], c);
  }
}

__global__ __launch_bounds__(512) void bucket_scan_kernel(const int* __restrict__ bucket_count,
    int* __restrict__ bucket_base, int* __restrict__ bucket_cursor, int nbk) {
  __shared__ int sh[512];
  int t = threadIdx.x;
  int v = (t < nbk) ? bucket_count[t] : 0;
  sh[t] = v;
  __syncthreads();
  for (int d = 1; d < 512; d <<= 1) {
    int u = (t >= d) ? sh[t - d] : 0;
    __syncthreads();
    sh[t] += u;
    __syncthreads();
  }
  if (t < nbk) {
    int ex = sh[t] - v;
    bucket_base[t] = ex;
    bucket_cursor[t] = ex;
  }
  if (t == 511) bucket_base[nbk] = sh[511];
}

// pairs packed: (src << 8) | (dst & 255); src < 2^17, bucket-local dst < 256
__global__ __launch_bounds__(256) void bucket_fill_kernel(const int* __restrict__ src,
    const int* __restrict__ dst, int* __restrict__ bucket_cursor,
    uint* __restrict__ pairs, int e, int nbk) {
  __shared__ int hist[512];
  int t = threadIdx.x;
  for (int i = t; i < nbk; i += 256) hist[i] = 0;
  __syncthreads();
  int lo = blockIdx.x * EPB;
  int hi = lo + EPB; if (hi > e) hi = e;
  for (int i = lo + t; i < hi; i += 256) atomicAdd(&hist[dst[i] >> BKT_SHIFT], 1);
  __syncthreads();
  for (int i = t; i < nbk; i += 256) {
    int c = hist[i];
    hist[i] = c ? atomicAdd(&bucket_cursor[i], c) : 0;   // hist now = write cursor
  }
  __syncthreads();
  for (int i = lo + t; i < hi; i += 256) {
    int s = src[i], d = dst[i];
    int pos = atomicAdd(&hist[d >> BKT_SHIFT], 1);
    pairs[pos] = ((uint)s << 8) | (uint)(d & 255);
  }
}

// one block per bucket: count per-node in LDS, scan -> offs & dinv, then scatter
__global__ __launch_bounds__(256) void bucket_scatter_kernel(const uint* __restrict__ pairs,
    const int* __restrict__ bucket_base, int* __restrict__ offs,
    float* __restrict__ dinv, int* __restrict__ csr_src, int n, int nbk) {
  __shared__ int cnt[256];
  __shared__ int pre[256];
  int b = blockIdx.x, t = threadIdx.x;
  int node0 = b << BKT_SHIFT;
  bool valid_node = (node0 + t) < n;
  cnt[t] = 0;
  __syncthreads();
  int lo = bucket_base[b], hi = bucket_base[b + 1];
  for (int i = lo + t; i < hi; i += 256)
    atomicAdd(&cnt[pairs[i] & 255u], 1);
  __syncthreads();
  int v = cnt[t];
  pre[t] = v;
  __syncthreads();
  for (int d = 1; d < 256; d <<= 1) {
    int u = (t >= d) ? pre[t - d] : 0;
    __syncthreads();
    pre[t] += u;
    __syncthreads();
  }
  int off = lo + pre[t] - v;   // exclusive prefix within bucket + bucket base
  if (valid_node) {
    offs[node0 + t] = off;
    dinv[node0 + t] = rsqrtf((float)(v + 1));   // +1: self-loop
  }
  __syncthreads();
  cnt[t] = off;   // reuse as cursor
  __syncthreads();
  for (int i = lo + t; i < hi; i += 256) {
    uint pp = pairs[i];
    int pos = atomicAdd(&cnt[pp & 255u], 1);
    csr_src[pos] = (int)(pp >> 8);
  }
  if (b == 0 && t == 0) offs[n] = bucket_base[nbk];
}

// ---------------- all weight transposes fused: wt[c][k] = bf16(W[k][c]) ------------
__global__ void convert_all_wt_kernel(const float* __restrict__ enc_w1,
    const float* __restrict__ enc_w2, const float* __restrict__ gcn_w,
    ushort* __restrict__ wt_e1, ushort* __restrict__ wt_e2, ushort* __restrict__ wt_g,
    int L) {
  const int S0 = 128 * FD, S1 = 128 * HD;
  int i = blockIdx.x * 256 + threadIdx.x;
  if (i < S0) {
    int c = i / FD, k = i - c * FD;
    wt_e1[i] = f2bf(enc_w1[k * 128 + c]);
  } else if (i < S0 + S1) {
    int j = i - S0;
    int c = j / HD, k = j - c * HD;
    wt_e2[j] = f2bf(enc_w2[k * 128 + c]);
  } else if (i < S0 + S1 + L * S1) {
    int j = i - S0 - S1;
    int l = j / S1, jj = j - l * S1;
    int c = jj / HD, k = jj - c * HD;
    wt_g[(size_t)l * S1 + jj] = f2bf(gcn_w[(size_t)l * HD * HD + k * 128 + c]);
  }
}

// ---------------- MFMA GEMM: C[M x 128] = A[M x K] @ W[K x 128] ----------------
// FP8OUT: write fp8(e4m3) of (o * dinv[row] * 16) -- GCN message rows.
// else:   write bf16 (+bias)(+relu).
template<typename TA, int K, bool BIAS, bool RELU, bool FP8OUT>
__global__ __launch_bounds__(256) void mfma_gemm_kernel(const TA* __restrict__ A,
    const ushort* __restrict__ Wt, const float* __restrict__ bias,
    void* __restrict__ Cout, const float* __restrict__ dinv, int M) {
  __shared__ ushort As[64 * K];
  __shared__ ushort Ws[128 * K];
  const int tid = threadIdx.x;
  const int r0 = blockIdx.x * 64;

  if constexpr (sizeof(TA) == 4) {
    constexpr int C4 = K / 4;
    const float4* A4 = (const float4*)A;
    #pragma unroll
    for (int i = tid; i < 64 * C4; i += 256) {
      int r = i / C4, c4 = i - r * C4;
      int row = r0 + r;
      float4 v = make_float4(0.f, 0.f, 0.f, 0.f);
      if (row < M) v = A4[(size_t)row * C4 + c4];
      ushort4 u;
      u.x = f2bf(v.x); u.y = f2bf(v.y); u.z = f2bf(v.z); u.w = f2bf(v.w);
      int elem = (r * K + c4 * 4) ^ ((r & 7) << 3);
      *(ushort4*)&As[elem] = u;
    }
  } else {
    constexpr int C8 = K / 8;
    const uint4* A4 = (const uint4*)A;
    #pragma unroll
    for (int i = tid; i < 64 * C8; i += 256) {
      int r = i / C8, c8 = i - r * C8;
      int row = r0 + r;
      uint4 v = make_uint4(0u, 0u, 0u, 0u);
      if (row < M) v = A4[(size_t)row * C8 + c8];
      int elem = (r * K + c8 * 8) ^ ((r & 7) << 3);
      *(uint4*)&As[elem] = v;
    }
  }
  {
    constexpr int C8 = K / 8;
    const uint4* W4 = (const uint4*)Wt;
    #pragma unroll
    for (int i = tid; i < 128 * C8; i += 256) {
      int c = i / C8, k8 = i - c * C8;
      uint4 v = W4[i];
      int elem = (c * K + k8 * 8) ^ ((c & 7) << 3);
      *(uint4*)&Ws[elem] = v;
    }
  }
  __syncthreads();

  const int l = tid & 63;
  const int wid = tid >> 6;
  const int lr = l & 15;       // fragment row/col within 16
  const int lk = l >> 4;       // k sub-block 0..3
  const int wr = wid * 16;     // wave's row base in tile
  f32x4 acc[8];
  #pragma unroll
  for (int cb = 0; cb < 8; ++cb) acc[cb] = (f32x4){0.f, 0.f, 0.f, 0.f};

  #pragma unroll
  for (int kc = 0; kc < K / 32; ++kc) {
    int ar = wr + lr;
    bf16x8 af = *(const bf16x8*)&As[(ar * K + kc * 32 + lk * 8) ^ ((ar & 7) << 3)];
    #pragma unroll
    for (int cb = 0; cb < 8; ++cb) {
      int col = cb * 16 + lr;
      bf16x8 bfr = *(const bf16x8*)&Ws[(col * K + kc * 32 + lk * 8) ^ ((col & 7) << 3)];
      acc[cb] = __builtin_amdgcn_mfma_f32_16x16x32_bf16(af, bfr, acc[cb], 0, 0, 0);
    }
  }

  if constexpr (FP8OUT) {
    uchar* C8p = (uchar*)Cout;
    float dv[4];
    #pragma unroll
    for (int j = 0; j < 4; ++j) {
      int row = r0 + wr + lk * 4 + j;
      dv[j] = (row < M) ? dinv[row] * FP8_SCALE : 0.f;
    }
    #pragma unroll
    for (int cb = 0; cb < 8; ++cb) {
      int col = cb * 16 + lr;
      #pragma unroll
      for (int j = 0; j < 4; ++j) {
        int row = r0 + wr + lk * 4 + j;
        if (row < M) {
          C8p[(size_t)row * 128 + col] = enc_fp8_byte(acc[cb][j] * dv[j]);
        }
      }
    }
  } else {
    ushort* Cb = (ushort*)Cout;
    #pragma unroll
    for (int cb = 0; cb < 8; ++cb) {
      int col = cb * 16 + lr;
      float bb = BIAS ? bias[col] : 0.f;
      #pragma unroll
      for (int j = 0; j < 4; ++j) {
        int row = r0 + wr + lk * 4 + j;
        if (row < M) {
          float o = acc[cb][j] + bb;
          if (RELU) o = fmaxf(o, 0.f);
          Cb[(size_t)row * 128 + col] = f2bf(o);
        }
      }
    }
  }
}

// ---------------- GCN aggregation + residual update (round-9 layout) ----------------
// xws rows are fp8: xws[i] = xw[i]*dinv[i]*16. Update:
//   x[i] (bf16) += relu( (dinv[i]/16) * (sum_{src} xws[src] + xws[i]) + bias )
// One wave per node; 4 edge-groups x 16 lanes (uint2 = 8 fp8 per lane);
// 4-deep unroll -> 16 rows in flight, 4 edges per gather instruction.
__global__ __launch_bounds__(256) void agg_update_kernel(
    const uchar* __restrict__ xws, ushort* __restrict__ x,
    const int* __restrict__ csr_src, const int* __restrict__ offs,
    const float* __restrict__ dinv, const float* __restrict__ bias, int n) {
  int node = blockIdx.x * 4 + (threadIdx.x >> 6);
  if (node >= n) return;
  int lane = threadIdx.x & 63;
  int grp = lane >> 4;       // edge group 0..3
  int cl = lane & 15;        // row chunk: dims 8*cl .. 8*cl+7
  const uint2* xw2 = (const uint2*)xws;   // row = 16 uint2 (128 fp8)
  float acc[8];
  #pragma unroll
  for (int k = 0; k < 8; ++k) acc[k] = 0.f;

  auto add_row = [&](uint2 v) {
    float f[4];
    dec_fp8x4(v.x, f);
    acc[0] += f[0]; acc[1] += f[1]; acc[2] += f[2]; acc[3] += f[3];
    dec_fp8x4(v.y, f);
    acc[4] += f[0]; acc[5] += f[1]; acc[6] += f[2]; acc[7] += f[3];
  };

  int beg = offs[node], end = offs[node + 1];
  int j = beg + grp;
  for (; j + 12 < end; j += 16) {
    int s0 = csr_src[j];
    int s1 = csr_src[j + 4];
    int s2 = csr_src[j + 8];
    int s3 = csr_src[j + 12];
    uint2 v0 = xw2[(size_t)s0 * 16 + cl];
    uint2 v1 = xw2[(size_t)s1 * 16 + cl];
    uint2 v2 = xw2[(size_t)s2 * 16 + cl];
    uint2 v3 = xw2[(size_t)s3 * 16 + cl];
    add_row(v0); add_row(v1); add_row(v2); add_row(v3);
  }
  for (; j + 4 < end; j += 8) {
    int s0 = csr_src[j];
    int s1 = csr_src[j + 4];
    uint2 v0 = xw2[(size_t)s0 * 16 + cl];
    uint2 v1 = xw2[(size_t)s1 * 16 + cl];
    add_row(v0); add_row(v1);
  }
  if (j < end) {
    uint2 v0 = xw2[(size_t)csr_src[j] * 16 + cl];
    add_row(v0);
  }
  if (grp == 0) {   // self-loop term
    uint2 vi = xw2[(size_t)node * 16 + cl];
    add_row(vi);
  }
  #pragma unroll
  for (int k = 0; k < 8; ++k) {
    acc[k] += __shfl_xor(acc[k], 16);
    acc[k] += __shfl_xor(acc[k], 32);
  }
  if (grp == 0) {
    float di = dinv[node] * FP8_INV_SCALE;
    const float4* b4 = (const float4*)bias;
    float4 bb0 = b4[cl * 2], bb1 = b4[cl * 2 + 1];
    float bbv[8] = {bb0.x, bb0.y, bb0.z, bb0.w, bb1.x, bb1.y, bb1.z, bb1.w};
    uint4* xv4 = (uint4*)x;
    size_t xi = (size_t)node * 16 + cl;
    uint4 xv = xv4[xi];
    uint xu[4] = {xv.x, xv.y, xv.z, xv.w};
    float o[8];
    #pragma unroll
    for (int q = 0; q < 4; ++q) {
      float lo = __uint_as_float(xu[q] << 16);
      float hi = __uint_as_float(xu[q] & 0xffff0000u);
      o[2 * q]     = fmaxf(fmaf(acc[2 * q],     di, bbv[2 * q]),     0.f) + lo;
      o[2 * q + 1] = fmaxf(fmaf(acc[2 * q + 1], di, bbv[2 * q + 1]), 0.f) + hi;
    }
    uint4 ou;
    ou.x = pack2bf(o[0], o[1]);
    ou.y = pack2bf(o[2], o[3]);
    ou.z = pack2bf(o[4], o[5]);
    ou.w = pack2bf(o[6], o[7]);
    xv4[xi] = ou;
  }
}

// ---------------- graph boundaries from sorted batch ----------------
__global__ void bounds_kernel(const int* __restrict__ batch, int* __restrict__ startg,
                              int n, int ng) {
  int i = blockIdx.x * blockDim.x + threadIdx.x;
  if (i > n) return;
  int bi = (i < n) ? batch[i] : ng;
  int bp = (i == 0) ? -1 : batch[i - 1];
  for (int g = bp + 1; g <= bi && g <= ng; ++g) startg[g] = i;
}

// ---------------- per-graph mean/max pooling: partial stage, vectorized ----------------
// 256 threads: 16 row-groups x 16 col-groups (uint4 = 8 bf16 per thread).
__global__ __launch_bounds__(256) void pool_partial_kernel(const ushort* __restrict__ x,
    const int* __restrict__ startg, float* __restrict__ psum, float* __restrict__ pmax) {
  __shared__ float ssum[16][128];
  __shared__ float smax[16][128];
  int g = blockIdx.x / PCH, ch = blockIdx.x % PCH;
  int t = threadIdx.x;
  int rg = t >> 4, cg = t & 15;
  int s0 = startg[g], s1 = startg[g + 1];
  int cnt = s1 - s0;
  int len = (cnt + PCH - 1) / PCH;
  int lo = s0 + ch * len;
  int hi = lo + len; if (hi > s1) hi = s1;
  float sum[8], mx[8];
  #pragma unroll
  for (int k = 0; k < 8; ++k) { sum[k] = 0.f; mx[k] = -INFINITY; }
  const uint4* x4 = (const uint4*)x;
  for (int r = lo + rg; r < hi; r += 16) {
    uint4 v = x4[(size_t)r * 16 + cg];
    uint uu[4] = {v.x, v.y, v.z, v.w};
    #pragma unroll
    for (int q = 0; q < 4; ++q) {
      float a = __uint_as_float(uu[q] << 16);
      float b = __uint_as_float(uu[q] & 0xffff0000u);
      sum[2 * q] += a;     mx[2 * q]     = fmaxf(mx[2 * q], a);
      sum[2 * q + 1] += b; mx[2 * q + 1] = fmaxf(mx[2 * q + 1], b);
    }
  }
  #pragma unroll
  for (int k = 0; k < 8; ++k) {
    ssum[rg][cg * 8 + k] = sum[k];
    smax[rg][cg * 8 + k] = mx[k];
  }
  __syncthreads();
  #pragma unroll
  for (int d = 8; d > 0; d >>= 1) {
    if (rg < d) {
      #pragma unroll
      for (int k = 0; k < 8; ++k) {
        int c = cg * 8 + k;
        ssum[rg][c] += ssum[rg + d][c];
        smax[rg][c] = fmaxf(smax[rg][c], smax[rg + d][c]);
      }
    }
    __syncthreads();
  }
  if (rg == 0) {
    #pragma unroll
    for (int k = 0; k < 8; ++k) {
      int c = cg * 8 + k;
      psum[(size_t)blockIdx.x * HD + c] = ssum[0][c];
      pmax[(size_t)blockIdx.x * HD + c] = smax[0][c];
    }
  }
}

// ---------------- pool-final + decoder + value heads (one block per graph) ----------
__global__ __launch_bounds__(128) void heads_kernel(
    const float* __restrict__ psum, const float* __restrict__ pmax,
    const int* __restrict__ startg,
    const float* __restrict__ dw1, const float* __restrict__ db1,
    const float* __restrict__ dw2, const float* __restrict__ db2,
    const float* __restrict__ dw3, const float* __restrict__ db3,
    const float* __restrict__ vw1, const float* __restrict__ vb1,
    const float* __restrict__ vw2, const float* __restrict__ vb2,
    float* __restrict__ out, int ng) {
  __shared__ float rep[256];
  __shared__ float h1[128];
  __shared__ float h2[64];
  __shared__ float v1[128];
  int g = blockIdx.x, t = threadIdx.x;
  {
    float sum = 0.f, mx = -INFINITY;
    #pragma unroll
    for (int ch = 0; ch < PCH; ++ch) {
      sum += psum[(size_t)(g * PCH + ch) * HD + t];
      mx = fmaxf(mx, pmax[(size_t)(g * PCH + ch) * HD + t]);
    }
    int cnt = startg[g + 1] - startg[g];
    float denom = (float)(cnt > 0 ? cnt : 1);
    rep[t] = sum / denom;
    rep[128 + t] = mx;
  }
  __syncthreads();
  float a = db1[t], b = vb1[t];
  for (int k = 0; k < 256; ++k) {
    float rv = rep[k];
    a = fmaf(rv, dw1[k * 128 + t], a);
    b = fmaf(rv, vw1[k * 128 + t], b);
  }
  h1[t] = fmaxf(a, 0.f);
  v1[t] = fmaxf(b, 0.f);
  __syncthreads();
  if (t < 64) {
    float c = db2[t];
    for (int k = 0; k < 128; ++k) c = fmaf(h1[k], dw2[k * 64 + t], c);
    h2[t] = fmaxf(c, 0.f);
  }
  __syncthreads();
  if (t == 0) {
    float l0 = db3[0], l2 = db3[2];
    for (int k = 0; k < 64; ++k) {
      l0 = fmaf(h2[k], dw3[k * 3 + 0], l0);
      l2 = fmaf(h2[k], dw3[k * 3 + 2], l2);
    }
    out[g] = 1.f / (1.f + expf(-l0));          // adaptation_prob
    out[ng + g] = 1.0f;                        // softmax over 1 element == 1
    out[2 * ng + g] = 1.f / (1.f + expf(-l2)); // urgency_score
    float v = vb2[0];
    for (int k = 0; k < 128; ++k) v = fmaf(v1[k], vw2[k], v);
    out[3 * ng + g] = v;                       // value_estimate
  }
}

// ---------------- launch ----------------
extern "C" void kernel_launch(void* const* d_in, const int* in_sizes, int n_in,
                              void* d_out, int out_size, void* d_ws, size_t ws_size,
                              hipStream_t stream) {
  const float* nf     = (const float*)d_in[0];
  const int*   ei     = (const int*)d_in[1];
  const int*   batch  = (const int*)d_in[2];
  const float* enc_w1 = (const float*)d_in[3];
  const float* enc_b1 = (const float*)d_in[4];
  const float* enc_w2 = (const float*)d_in[5];
  const float* enc_b2 = (const float*)d_in[6];
  const float* gcn_w  = (const float*)d_in[7];
  const float* gcn_b  = (const float*)d_in[8];
  const float* dec_w1 = (const float*)d_in[9];
  const float* dec_b1 = (const float*)d_in[10];
  const float* dec_w2 = (const float*)d_in[11];
  const float* dec_b2 = (const float*)d_in[12];
  const float* dec_w3 = (const float*)d_in[13];
  const float* dec_b3 = (const float*)d_in[14];
  const float* val_w1 = (const float*)d_in[15];
  const float* val_b1 = (const float*)d_in[16];
  const float* val_w2 = (const float*)d_in[17];
  const float* val_b2 = (const float*)d_in[18];
  float* out = (float*)d_out;

  const int n = in_sizes[0] / FD;           // 100000
  const int e = in_sizes[1] / 2;            // 1600000
  const int L = in_sizes[7] / (HD * HD);    // 3
  const int G = out_size / 4;               // 64

  // workspace carve
  char* p = (char*)d_ws;
  auto carve = [&](size_t bytes) {
    void* r = (void*)p;
    p += (bytes + 255) & ~(size_t)255;
    return r;
  };
  ushort* x       = (ushort*)carve((size_t)n * HD * 2);    // bf16 x
  ushort* xwb     = (ushort*)carve((size_t)n * HD * 2);    // bf16 encoder tmp
  uchar*  xw8     = (uchar*)carve((size_t)n * HD);         // fp8 message rows
  float*  dinv    = (float*)carve((size_t)n * 4);
  int*    offs    = (int*)carve((size_t)(n + 1) * 4);
  int*    csr_src = (int*)carve((size_t)e * 4);
  int*    startg  = (int*)carve((size_t)(G + 1) * 4);
  float*  psum    = (float*)carve((size_t)G * PCH * HD * 4);
  float*  pmax    = (float*)carve((size_t)G * PCH * HD * 4);
  const int nbk   = (n + (1 << BKT_SHIFT) - 1) >> BKT_SHIFT;   // 391 buckets
  int*    bucket_count  = (int*)carve((size_t)nbk * 4);
  int*    bucket_base   = (int*)carve((size_t)(nbk + 1) * 4);
  int*    bucket_cursor = (int*)carve((size_t)nbk * 4);
  ushort* wt_e1   = (ushort*)carve((size_t)128 * FD * 2);      // enc_w1^T bf16
  ushort* wt_e2   = (ushort*)carve((size_t)128 * HD * 2);      // enc_w2^T bf16
  ushort* wt_g    = (ushort*)carve((size_t)3 * 128 * HD * 2);  // gcn_w^T bf16
  // pairs aliases xwb: CSR build completes before enc1 writes xwb (stream-ordered)
  uint*   pairs   = (uint*)xwb;

  const int gemm_grid = (n + 63) / 64;
  const int ebk_grid = (e + EPB - 1) / EPB;

  // ---- graph structure (before encoder so pairs can alias xwb) ----
  zero_int_kernel<<<(nbk + 255) / 256, 256, 0, stream>>>(bucket_count, nbk);
  bucket_count_kernel<<<ebk_grid, 256, 0, stream>>>(ei + e, bucket_count, e, nbk);
  bucket_scan_kernel<<<1, 512, 0, stream>>>(bucket_count, bucket_base, bucket_cursor, nbk);
  bucket_fill_kernel<<<ebk_grid, 256, 0, stream>>>(ei, ei + e, bucket_cursor, pairs, e, nbk);
  bucket_scatter_kernel<<<nbk, 256, 0, stream>>>(pairs, bucket_base, offs, dinv, csr_src, n, nbk);

  // ---- weight transposes (one kernel) ----
  {
    int tot = 128 * FD + 128 * HD + L * 128 * HD;
    convert_all_wt_kernel<<<(tot + 255) / 256, 256, 0, stream>>>(
        enc_w1, enc_w2, gcn_w, wt_e1, wt_e2, wt_g, L);
  }

  // ---- encoder: nf @ w1 -> relu (bf16), @ w2 -> x (bf16) ----
  mfma_gemm_kernel<float, FD, true, true, false><<<gemm_grid, 256, 0, stream>>>(
      nf, wt_e1, enc_b1, xwb, nullptr, n);
  mfma_gemm_kernel<ushort, HD, true, false, false><<<gemm_grid, 256, 0, stream>>>(
      xwb, wt_e2, enc_b2, x, nullptr, n);

  // ---- GCN layers: GEMM writes fp8 rows pre-scaled by dinv*16 ----
  for (int l = 0; l < L; ++l) {
    mfma_gemm_kernel<ushort, HD, false, false, true><<<gemm_grid, 256, 0, stream>>>(
        x, wt_g + (size_t)l * 128 * HD, nullptr, xw8, dinv, n);
    agg_update_kernel<<<(n + 3) / 4, 256, 0, stream>>>(
        xw8, x, csr_src, offs, dinv, gcn_b + (size_t)l * HD, n);
  }

  // ---- pooling + heads ----
  bounds_kernel<<<(n + 1 + 255) / 256, 256, 0, stream>>>(batch, startg, n, G);
  pool_partial_kernel<<<G * PCH, 256, 0, stream>>>(x, startg, psum, pmax);
  heads_kernel<<<G, 128, 0, stream>>>(psum, pmax, startg,
      dec_w1, dec_b1, dec_w2, dec_b2, dec_w3, dec_b3,
      val_w1, val_b1, val_w2, val_b2, out, G);
}

// Round 12
// 359.854 us; speedup vs baseline: 1.1004x; 1.0383x over previous
//
#include <hip/hip_runtime.h>
#include <math.h>

constexpr int HD = 128;   // hidden dim
constexpr int FD = 64;    // input feature dim
constexpr int PCH = 32;   // pooling chunks per graph
constexpr int BKT_SHIFT = 8;           // 256 nodes per bucket
constexpr int EPB = 2048;              // edges per block in bucket passes
constexpr float FP8_SCALE = 16.f;      // pre-scale before e4m3 quantization
constexpr float FP8_INV_SCALE = 1.f / 16.f;

typedef unsigned int uint;
typedef unsigned short ushort;
typedef unsigned char uchar;

using bf16x8 = __attribute__((ext_vector_type(8))) short;   // 4 VGPRs
using f32x4  = __attribute__((ext_vector_type(4))) float;

#if defined(__has_builtin)
#if __has_builtin(__builtin_amdgcn_cvt_pk_f32_fp8) && __has_builtin(__builtin_amdgcn_cvt_pk_fp8_f32)
#define HW_FP8 1
#endif
#endif

static __device__ inline ushort f2bf(float f) {   // round-to-nearest-even bf16
  uint u = __float_as_uint(f);
  return (ushort)((u + 0x7fffu + ((u >> 16) & 1u)) >> 16);
}
static __device__ inline float bf2f(ushort b) {
  return __uint_as_float((uint)b << 16);
}
static __device__ inline uint pack2bf(float a, float b) {
  return (uint)f2bf(a) | ((uint)f2bf(b) << 16);
}

// ---- fp8 e4m3 (OCP) helpers: HW path + fallback ----
static __device__ inline uchar enc_fp8_byte(float f) {
#ifdef HW_FP8
  return (uchar)(__builtin_amdgcn_cvt_pk_fp8_f32(f, f, 0, false) & 0xff);
#else
  float a = fabsf(f);
  uint s = (f < 0.f) ? 0x80u : 0u;
  if (!(a > 0.f)) return (uchar)s;
  a = fminf(a, 448.f);
  uint b = __float_as_uint(a);
  int e = (int)(b >> 23) - 127;
  if (e < -6) {                       // denormal domain: multiples of 2^-9
    int q = (int)rintf(a * 512.f);
    if (q <= 0) return (uchar)s;
    if (q >= 8) return (uchar)(s | 0x08u);
    return (uchar)(s | (uint)q);
  }
  uint r = b + 0x7ffffu + ((b >> 20) & 1u);   // RTN-even at mantissa bit 20
  uint m = (r >> 20) & 7u;
  int ee = (int)(r >> 23) - 127 + 7;
  if (ee <= 0) return (uchar)(s | 0x08u);
  if (ee > 15) return (uchar)(s | 0x7eu);
  return (uchar)(s | ((uint)ee << 3) | m);
#endif
}

static __device__ inline float dec_fp8_byte(uint em_s) {   // fallback scalar decode
  uint s = (em_s & 0x80u) << 24;
  uint em = em_s & 0x7fu;
  float v;
  if (em < 8) v = (float)em * (1.f / 512.f);
  else v = __uint_as_float((em + (120u << 3)) << 20);
  return __uint_as_float(__float_as_uint(v) | s);
}

static __device__ inline void dec_fp8x4(uint u, float* dst) {
#ifdef HW_FP8
  auto a = __builtin_amdgcn_cvt_pk_f32_fp8((int)u, false);
  auto b = __builtin_amdgcn_cvt_pk_f32_fp8((int)u, true);
  dst[0] = a[0]; dst[1] = a[1]; dst[2] = b[0]; dst[3] = b[1];
#else
  dst[0] = dec_fp8_byte(u & 0xffu);
  dst[1] = dec_fp8_byte((u >> 8) & 0xffu);
  dst[2] = dec_fp8_byte((u >> 16) & 0xffu);
  dst[3] = dec_fp8_byte(u >> 24);
#endif
}

// ---------------- utility ----------------
__global__ void zero_int_kernel(int* __restrict__ p, int n) {
  int i = blockIdx.x * blockDim.x + threadIdx.x;
  if (i < n) p[i] = 0;
}

// ---------------- bucketed CSR build (also produces offs, dinv) ----------------
__global__ __launch_bounds__(256) void bucket_count_kernel(const int* __restrict__ dst,
    int* __restrict__ bucket_count, int e, int nbk) {
  __shared__ int hist[512];
  int t = threadIdx.x;
  for (int i = t; i < nbk; i += 256) hist[i] = 0;
  __syncthreads();
  int lo = blockIdx.x * EPB;
  int hi = lo + EPB; if (hi > e) hi = e;
  for (int i = lo + t; i < hi; i += 256) atomicAdd(&hist[dst[i] >> BKT_SHIFT], 1);
  __syncthreads();
  for (int i = t; i < nbk; i += 256) {
    int c = hist[i];
    if (c) atomicAdd(&bucket_count[i], c);
  }
}

__global__ __launch_bounds__(512) void bucket_scan_kernel(const int* __restrict__ bucket_count,
    int* __restrict__ bucket_base, int* __restrict__ bucket_cursor, int nbk) {
  __shared__ int sh[512];
  int t = threadIdx.x;
  int v = (t < nbk) ? bucket_count[t] : 0;
  sh[t] = v;
  __syncthreads();
  for (int d = 1; d < 512; d <<= 1) {
    int u = (t >= d) ? sh[t - d] : 0;
    __syncthreads();
    sh[t] += u;
    __syncthreads();
  }
  if (t < nbk) {
    int ex = sh[t] - v;
    bucket_base[t] = ex;
    bucket_cursor[t] = ex;
  }
  if (t == 511) bucket_base[nbk] = sh[511];
}

// pairs packed: (src << 8) | (dst & 255); src < 2^17, bucket-local dst < 256
__global__ __launch_bounds__(256) void bucket_fill_kernel(const int* __restrict__ src,
    const int* __restrict__ dst, int* __restrict__ bucket_cursor,
    uint* __restrict__ pairs, int e, int nbk) {
  __shared__ int hist[512];
  int t = threadIdx.x;
  for (int i = t; i < nbk; i += 256) hist[i] = 0;
  __syncthreads();
  int lo = blockIdx.x * EPB;
  int hi = lo + EPB; if (hi > e) hi = e;
  for (int i = lo + t; i < hi; i += 256) atomicAdd(&hist[dst[i] >> BKT_SHIFT], 1);
  __syncthreads();
  for (int i = t; i < nbk; i += 256) {
    int c = hist[i];
    hist[i] = c ? atomicAdd(&bucket_cursor[i], c) : 0;   // hist now = write cursor
  }
  __syncthreads();
  for (int i = lo + t; i < hi; i += 256) {
    int s = src[i], d = dst[i];
    int pos = atomicAdd(&hist[d >> BKT_SHIFT], 1);
    pairs[pos] = ((uint)s << 8) | (uint)(d & 255);
  }
}

// one block per bucket: count per-node in LDS, scan -> offs & dinv, then scatter
__global__ __launch_bounds__(256) void bucket_scatter_kernel(const uint* __restrict__ pairs,
    const int* __restrict__ bucket_base, int* __restrict__ offs,
    float* __restrict__ dinv, int* __restrict__ csr_src, int n, int nbk) {
  __shared__ int cnt[256];
  __shared__ int pre[256];
  int b = blockIdx.x, t = threadIdx.x;
  int node0 = b << BKT_SHIFT;
  bool valid_node = (node0 + t) < n;
  cnt[t] = 0;
  __syncthreads();
  int lo = bucket_base[b], hi = bucket_base[b + 1];
  for (int i = lo + t; i < hi; i += 256)
    atomicAdd(&cnt[pairs[i] & 255u], 1);
  __syncthreads();
  int v = cnt[t];
  pre[t] = v;
  __syncthreads();
  for (int d = 1; d < 256; d <<= 1) {
    int u = (t >= d) ? pre[t - d] : 0;
    __syncthreads();
    pre[t] += u;
    __syncthreads();
  }
  int off = lo + pre[t] - v;   // exclusive prefix within bucket + bucket base
  if (valid_node) {
    offs[node0 + t] = off;
    dinv[node0 + t] = rsqrtf((float)(v + 1));   // +1: self-loop
  }
  __syncthreads();
  cnt[t] = off;   // reuse as cursor
  __syncthreads();
  for (int i = lo + t; i < hi; i += 256) {
    uint pp = pairs[i];
    int pos = atomicAdd(&cnt[pp & 255u], 1);
    csr_src[pos] = (int)(pp >> 8);
  }
  if (b == 0 && t == 0) offs[n] = bucket_base[nbk];
}

// ---------------- all weight transposes fused: wt[c][k] = bf16(W[k][c]) ------------
__global__ void convert_all_wt_kernel(const float* __restrict__ enc_w1,
    const float* __restrict__ enc_w2, const float* __restrict__ gcn_w,
    ushort* __restrict__ wt_e1, ushort* __restrict__ wt_e2, ushort* __restrict__ wt_g,
    int L) {
  const int S0 = 128 * FD, S1 = 128 * HD;
  int i = blockIdx.x * 256 + threadIdx.x;
  if (i < S0) {
    int c = i / FD, k = i - c * FD;
    wt_e1[i] = f2bf(enc_w1[k * 128 + c]);
  } else if (i < S0 + S1) {
    int j = i - S0;
    int c = j / HD, k = j - c * HD;
    wt_e2[j] = f2bf(enc_w2[k * 128 + c]);
  } else if (i < S0 + S1 + L * S1) {
    int j = i - S0 - S1;
    int l = j / S1, jj = j - l * S1;
    int c = jj / HD, k = jj - c * HD;
    wt_g[(size_t)l * S1 + jj] = f2bf(gcn_w[(size_t)l * HD * HD + k * 128 + c]);
  }
}

// ---------------- fused encoder: x = relu(nf@W1+b1)@W2 + b2  (bf16 out) -----------
// Per 64-row tile: stage nf (f32->bf16) + W1t + W2t in LDS; GEMM1 -> Mid (LDS, relu);
// GEMM2 -> x. LDS total 72KB -> 2 blocks/CU.
__global__ __launch_bounds__(256) void encoder_fused_kernel(
    const float* __restrict__ nf, const ushort* __restrict__ wt1,
    const float* __restrict__ b1, const ushort* __restrict__ wt2,
    const float* __restrict__ b2, ushort* __restrict__ xout, int M) {
  __shared__ ushort As[64 * FD];     // 8 KB
  __shared__ ushort W1s[128 * FD];   // 16 KB
  __shared__ ushort Mid[64 * HD];    // 16 KB
  __shared__ ushort W2s[128 * HD];   // 32 KB
  const int tid = threadIdx.x;
  const int r0 = blockIdx.x * 64;

  // stage A (f32 -> bf16), swizzled
  {
    constexpr int C4 = FD / 4;   // 16 float4 per row
    const float4* A4 = (const float4*)nf;
    #pragma unroll
    for (int i = tid; i < 64 * C4; i += 256) {
      int r = i / C4, c4 = i - r * C4;
      int row = r0 + r;
      float4 v = make_float4(0.f, 0.f, 0.f, 0.f);
      if (row < M) v = A4[(size_t)row * C4 + c4];
      ushort4 u;
      u.x = f2bf(v.x); u.y = f2bf(v.y); u.z = f2bf(v.z); u.w = f2bf(v.w);
      int elem = (r * FD + c4 * 4) ^ ((r & 7) << 3);
      *(ushort4*)&As[elem] = u;
    }
  }
  // stage W1t [128][64], swizzled
  {
    constexpr int C8 = FD / 8;   // 8 uint4 per row
    const uint4* W4 = (const uint4*)wt1;
    #pragma unroll
    for (int i = tid; i < 128 * C8; i += 256) {
      int c = i / C8, k8 = i - c * C8;
      uint4 v = W4[i];
      int elem = (c * FD + k8 * 8) ^ ((c & 7) << 3);
      *(uint4*)&W1s[elem] = v;
    }
  }
  // stage W2t [128][128], swizzled
  {
    constexpr int C8 = HD / 8;   // 16 uint4 per row
    const uint4* W4 = (const uint4*)wt2;
    #pragma unroll
    for (int i = tid; i < 128 * C8; i += 256) {
      int c = i / C8, k8 = i - c * C8;
      uint4 v = W4[i];
      int elem = (c * HD + k8 * 8) ^ ((c & 7) << 3);
      *(uint4*)&W2s[elem] = v;
    }
  }
  __syncthreads();

  const int l = tid & 63;
  const int wid = tid >> 6;
  const int lr = l & 15;
  const int lk = l >> 4;
  const int wr = wid * 16;

  // ---- GEMM1: Mid = relu(A @ W1 + b1) ----
  {
    f32x4 acc[8];
    #pragma unroll
    for (int cb = 0; cb < 8; ++cb) acc[cb] = (f32x4){0.f, 0.f, 0.f, 0.f};
    #pragma unroll
    for (int kc = 0; kc < FD / 32; ++kc) {
      int ar = wr + lr;
      bf16x8 af = *(const bf16x8*)&As[(ar * FD + kc * 32 + lk * 8) ^ ((ar & 7) << 3)];
      #pragma unroll
      for (int cb = 0; cb < 8; ++cb) {
        int col = cb * 16 + lr;
        bf16x8 bfr = *(const bf16x8*)&W1s[(col * FD + kc * 32 + lk * 8) ^ ((col & 7) << 3)];
        acc[cb] = __builtin_amdgcn_mfma_f32_16x16x32_bf16(af, bfr, acc[cb], 0, 0, 0);
      }
    }
    #pragma unroll
    for (int cb = 0; cb < 8; ++cb) {
      int col = cb * 16 + lr;
      float bb = b1[col];
      #pragma unroll
      for (int j = 0; j < 4; ++j) {
        int row = wr + lk * 4 + j;
        float o = fmaxf(acc[cb][j] + bb, 0.f);
        Mid[(row * HD + col) ^ ((row & 7) << 3)] = f2bf(o);
      }
    }
  }
  __syncthreads();

  // ---- GEMM2: x = Mid @ W2 + b2 ----
  {
    f32x4 acc[8];
    #pragma unroll
    for (int cb = 0; cb < 8; ++cb) acc[cb] = (f32x4){0.f, 0.f, 0.f, 0.f};
    #pragma unroll
    for (int kc = 0; kc < HD / 32; ++kc) {
      int ar = wr + lr;
      bf16x8 af = *(const bf16x8*)&Mid[(ar * HD + kc * 32 + lk * 8) ^ ((ar & 7) << 3)];
      #pragma unroll
      for (int cb = 0; cb < 8; ++cb) {
        int col = cb * 16 + lr;
        bf16x8 bfr = *(const bf16x8*)&W2s[(col * HD + kc * 32 + lk * 8) ^ ((col & 7) << 3)];
        acc[cb] = __builtin_amdgcn_mfma_f32_16x16x32_bf16(af, bfr, acc[cb], 0, 0, 0);
      }
    }
    #pragma unroll
    for (int cb = 0; cb < 8; ++cb) {
      int col = cb * 16 + lr;
      float bb = b2[col];
      #pragma unroll
      for (int j = 0; j < 4; ++j) {
        int row = r0 + wr + lk * 4 + j;
        if (row < M) xout[(size_t)row * 128 + col] = f2bf(acc[cb][j] + bb);
      }
    }
  }
}

// ---------------- multi-tile MFMA GEMM (GCN layers): fp8 out, dinv*16 folded ------
// Wt staged once per block; grid-stride loop over 64-row tiles.
__global__ __launch_bounds__(256) void mfma_gemm_fp8_kernel(const ushort* __restrict__ A,
    const ushort* __restrict__ Wt, uchar* __restrict__ Cout,
    const float* __restrict__ dinv, int M, int ntiles) {
  __shared__ ushort As[64 * HD];    // 16 KB
  __shared__ ushort Ws[128 * HD];   // 32 KB
  const int tid = threadIdx.x;

  // stage Wt once
  {
    constexpr int C8 = HD / 8;
    const uint4* W4 = (const uint4*)Wt;
    #pragma unroll
    for (int i = tid; i < 128 * C8; i += 256) {
      int c = i / C8, k8 = i - c * C8;
      uint4 v = W4[i];
      int elem = (c * HD + k8 * 8) ^ ((c & 7) << 3);
      *(uint4*)&Ws[elem] = v;
    }
  }

  const int l = tid & 63;
  const int wid = tid >> 6;
  const int lr = l & 15;
  const int lk = l >> 4;
  const int wr = wid * 16;

  for (int tile = blockIdx.x; tile < ntiles; tile += gridDim.x) {
    __syncthreads();   // Ws ready / prior-tile As readers done
    const int r0 = tile * 64;
    {
      constexpr int C8 = HD / 8;
      const uint4* A4 = (const uint4*)A;
      #pragma unroll
      for (int i = tid; i < 64 * C8; i += 256) {
        int r = i / C8, c8 = i - r * C8;
        int row = r0 + r;
        uint4 v = make_uint4(0u, 0u, 0u, 0u);
        if (row < M) v = A4[(size_t)row * C8 + c8];
        int elem = (r * HD + c8 * 8) ^ ((r & 7) << 3);
        *(uint4*)&As[elem] = v;
      }
    }
    __syncthreads();

    f32x4 acc[8];
    #pragma unroll
    for (int cb = 0; cb < 8; ++cb) acc[cb] = (f32x4){0.f, 0.f, 0.f, 0.f};
    #pragma unroll
    for (int kc = 0; kc < HD / 32; ++kc) {
      int ar = wr + lr;
      bf16x8 af = *(const bf16x8*)&As[(ar * HD + kc * 32 + lk * 8) ^ ((ar & 7) << 3)];
      #pragma unroll
      for (int cb = 0; cb < 8; ++cb) {
        int col = cb * 16 + lr;
        bf16x8 bfr = *(const bf16x8*)&Ws[(col * HD + kc * 32 + lk * 8) ^ ((col & 7) << 3)];
        acc[cb] = __builtin_amdgcn_mfma_f32_16x16x32_bf16(af, bfr, acc[cb], 0, 0, 0);
      }
    }

    float dv[4];
    #pragma unroll
    for (int j = 0; j < 4; ++j) {
      int row = r0 + wr + lk * 4 + j;
      dv[j] = (row < M) ? dinv[row] * FP8_SCALE : 0.f;
    }
    #pragma unroll
    for (int cb = 0; cb < 8; ++cb) {
      int col = cb * 16 + lr;
      #pragma unroll
      for (int j = 0; j < 4; ++j) {
        int row = r0 + wr + lk * 4 + j;
        if (row < M) {
          Cout[(size_t)row * 128 + col] = enc_fp8_byte(acc[cb][j] * dv[j]);
        }
      }
    }
  }
}

// ---------------- GCN aggregation + residual update (round-9 layout, unchanged) ----
__global__ __launch_bounds__(256) void agg_update_kernel(
    const uchar* __restrict__ xws, ushort* __restrict__ x,
    const int* __restrict__ csr_src, const int* __restrict__ offs,
    const float* __restrict__ dinv, const float* __restrict__ bias, int n) {
  int node = blockIdx.x * 4 + (threadIdx.x >> 6);
  if (node >= n) return;
  int lane = threadIdx.x & 63;
  int grp = lane >> 4;       // edge group 0..3
  int cl = lane & 15;        // row chunk: dims 8*cl .. 8*cl+7
  const uint2* xw2 = (const uint2*)xws;   // row = 16 uint2 (128 fp8)
  float acc[8];
  #pragma unroll
  for (int k = 0; k < 8; ++k) acc[k] = 0.f;

  auto add_row = [&](uint2 v) {
    float f[4];
    dec_fp8x4(v.x, f);
    acc[0] += f[0]; acc[1] += f[1]; acc[2] += f[2]; acc[3] += f[3];
    dec_fp8x4(v.y, f);
    acc[4] += f[0]; acc[5] += f[1]; acc[6] += f[2]; acc[7] += f[3];
  };

  int beg = offs[node], end = offs[node + 1];
  int j = beg + grp;
  for (; j + 12 < end; j += 16) {
    int s0 = csr_src[j];
    int s1 = csr_src[j + 4];
    int s2 = csr_src[j + 8];
    int s3 = csr_src[j + 12];
    uint2 v0 = xw2[(size_t)s0 * 16 + cl];
    uint2 v1 = xw2[(size_t)s1 * 16 + cl];
    uint2 v2 = xw2[(size_t)s2 * 16 + cl];
    uint2 v3 = xw2[(size_t)s3 * 16 + cl];
    add_row(v0); add_row(v1); add_row(v2); add_row(v3);
  }
  for (; j + 4 < end; j += 8) {
    int s0 = csr_src[j];
    int s1 = csr_src[j + 4];
    uint2 v0 = xw2[(size_t)s0 * 16 + cl];
    uint2 v1 = xw2[(size_t)s1 * 16 + cl];
    add_row(v0); add_row(v1);
  }
  if (j < end) {
    uint2 v0 = xw2[(size_t)csr_src[j] * 16 + cl];
    add_row(v0);
  }
  if (grp == 0) {   // self-loop term
    uint2 vi = xw2[(size_t)node * 16 + cl];
    add_row(vi);
  }
  #pragma unroll
  for (int k = 0; k < 8; ++k) {
    acc[k] += __shfl_xor(acc[k], 16);
    acc[k] += __shfl_xor(acc[k], 32);
  }
  if (grp == 0) {
    float di = dinv[node] * FP8_INV_SCALE;
    const float4* b4 = (const float4*)bias;
    float4 bb0 = b4[cl * 2], bb1 = b4[cl * 2 + 1];
    float bbv[8] = {bb0.x, bb0.y, bb0.z, bb0.w, bb1.x, bb1.y, bb1.z, bb1.w};
    uint4* xv4 = (uint4*)x;
    size_t xi = (size_t)node * 16 + cl;
    uint4 xv = xv4[xi];
    uint xu[4] = {xv.x, xv.y, xv.z, xv.w};
    float o[8];
    #pragma unroll
    for (int q = 0; q < 4; ++q) {
      float lo = __uint_as_float(xu[q] << 16);
      float hi = __uint_as_float(xu[q] & 0xffff0000u);
      o[2 * q]     = fmaxf(fmaf(acc[2 * q],     di, bbv[2 * q]),     0.f) + lo;
      o[2 * q + 1] = fmaxf(fmaf(acc[2 * q + 1], di, bbv[2 * q + 1]), 0.f) + hi;
    }
    uint4 ou;
    ou.x = pack2bf(o[0], o[1]);
    ou.y = pack2bf(o[2], o[3]);
    ou.z = pack2bf(o[4], o[5]);
    ou.w = pack2bf(o[6], o[7]);
    xv4[xi] = ou;
  }
}

// ---------------- graph boundaries from sorted batch ----------------
__global__ void bounds_kernel(const int* __restrict__ batch, int* __restrict__ startg,
                              int n, int ng) {
  int i = blockIdx.x * blockDim.x + threadIdx.x;
  if (i > n) return;
  int bi = (i < n) ? batch[i] : ng;
  int bp = (i == 0) ? -1 : batch[i - 1];
  for (int g = bp + 1; g <= bi && g <= ng; ++g) startg[g] = i;
}

// ---------------- per-graph mean/max pooling: partial stage, vectorized ----------------
__global__ __launch_bounds__(256) void pool_partial_kernel(const ushort* __restrict__ x,
    const int* __restrict__ startg, float* __restrict__ psum, float* __restrict__ pmax) {
  __shared__ float ssum[16][128];
  __shared__ float smax[16][128];
  int g = blockIdx.x / PCH, ch = blockIdx.x % PCH;
  int t = threadIdx.x;
  int rg = t >> 4, cg = t & 15;
  int s0 = startg[g], s1 = startg[g + 1];
  int cnt = s1 - s0;
  int len = (cnt + PCH - 1) / PCH;
  int lo = s0 + ch * len;
  int hi = lo + len; if (hi > s1) hi = s1;
  float sum[8], mx[8];
  #pragma unroll
  for (int k = 0; k < 8; ++k) { sum[k] = 0.f; mx[k] = -INFINITY; }
  const uint4* x4 = (const uint4*)x;
  for (int r = lo + rg; r < hi; r += 16) {
    uint4 v = x4[(size_t)r * 16 + cg];
    uint uu[4] = {v.x, v.y, v.z, v.w};
    #pragma unroll
    for (int q = 0; q < 4; ++q) {
      float a = __uint_as_float(uu[q] << 16);
      float b = __uint_as_float(uu[q] & 0xffff0000u);
      sum[2 * q] += a;     mx[2 * q]     = fmaxf(mx[2 * q], a);
      sum[2 * q + 1] += b; mx[2 * q + 1] = fmaxf(mx[2 * q + 1], b);
    }
  }
  #pragma unroll
  for (int k = 0; k < 8; ++k) {
    ssum[rg][cg * 8 + k] = sum[k];
    smax[rg][cg * 8 + k] = mx[k];
  }
  __syncthreads();
  #pragma unroll
  for (int d = 8; d > 0; d >>= 1) {
    if (rg < d) {
      #pragma unroll
      for (int k = 0; k < 8; ++k) {
        int c = cg * 8 + k;
        ssum[rg][c] += ssum[rg + d][c];
        smax[rg][c] = fmaxf(smax[rg][c], smax[rg + d][c]);
      }
    }
    __syncthreads();
  }
  if (rg == 0) {
    #pragma unroll
    for (int k = 0; k < 8; ++k) {
      int c = cg * 8 + k;
      psum[(size_t)blockIdx.x * HD + c] = ssum[0][c];
      pmax[(size_t)blockIdx.x * HD + c] = smax[0][c];
    }
  }
}

// ---------------- pool-final + decoder + value heads (one block per graph) ----------
__global__ __launch_bounds__(128) void heads_kernel(
    const float* __restrict__ psum, const float* __restrict__ pmax,
    const int* __restrict__ startg,
    const float* __restrict__ dw1, const float* __restrict__ db1,
    const float* __restrict__ dw2, const float* __restrict__ db2,
    const float* __restrict__ dw3, const float* __restrict__ db3,
    const float* __restrict__ vw1, const float* __restrict__ vb1,
    const float* __restrict__ vw2, const float* __restrict__ vb2,
    float* __restrict__ out, int ng) {
  __shared__ float rep[256];
  __shared__ float h1[128];
  __shared__ float h2[64];
  __shared__ float v1[128];
  int g = blockIdx.x, t = threadIdx.x;
  {
    float sum = 0.f, mx = -INFINITY;
    #pragma unroll
    for (int ch = 0; ch < PCH; ++ch) {
      sum += psum[(size_t)(g * PCH + ch) * HD + t];
      mx = fmaxf(mx, pmax[(size_t)(g * PCH + ch) * HD + t]);
    }
    int cnt = startg[g + 1] - startg[g];
    float denom = (float)(cnt > 0 ? cnt : 1);
    rep[t] = sum / denom;
    rep[128 + t] = mx;
  }
  __syncthreads();
  float a = db1[t], b = vb1[t];
  for (int k = 0; k < 256; ++k) {
    float rv = rep[k];
    a = fmaf(rv, dw1[k * 128 + t], a);
    b = fmaf(rv, vw1[k * 128 + t], b);
  }
  h1[t] = fmaxf(a, 0.f);
  v1[t] = fmaxf(b, 0.f);
  __syncthreads();
  if (t < 64) {
    float c = db2[t];
    for (int k = 0; k < 128; ++k) c = fmaf(h1[k], dw2[k * 64 + t], c);
    h2[t] = fmaxf(c, 0.f);
  }
  __syncthreads();
  if (t == 0) {
    float l0 = db3[0], l2 = db3[2];
    for (int k = 0; k < 64; ++k) {
      l0 = fmaf(h2[k], dw3[k * 3 + 0], l0);
      l2 = fmaf(h2[k], dw3[k * 3 + 2], l2);
    }
    out[g] = 1.f / (1.f + expf(-l0));          // adaptation_prob
    out[ng + g] = 1.0f;                        // softmax over 1 element == 1
    out[2 * ng + g] = 1.f / (1.f + expf(-l2)); // urgency_score
    float v = vb2[0];
    for (int k = 0; k < 128; ++k) v = fmaf(v1[k], vw2[k], v);
    out[3 * ng + g] = v;                       // value_estimate
  }
}

// ---------------- launch ----------------
extern "C" void kernel_launch(void* const* d_in, const int* in_sizes, int n_in,
                              void* d_out, int out_size, void* d_ws, size_t ws_size,
                              hipStream_t stream) {
  const float* nf     = (const float*)d_in[0];
  const int*   ei     = (const int*)d_in[1];
  const int*   batch  = (const int*)d_in[2];
  const float* enc_w1 = (const float*)d_in[3];
  const float* enc_b1 = (const float*)d_in[4];
  const float* enc_w2 = (const float*)d_in[5];
  const float* enc_b2 = (const float*)d_in[6];
  const float* gcn_w  = (const float*)d_in[7];
  const float* gcn_b  = (const float*)d_in[8];
  const float* dec_w1 = (const float*)d_in[9];
  const float* dec_b1 = (const float*)d_in[10];
  const float* dec_w2 = (const float*)d_in[11];
  const float* dec_b2 = (const float*)d_in[12];
  const float* dec_w3 = (const float*)d_in[13];
  const float* dec_b3 = (const float*)d_in[14];
  const float* val_w1 = (const float*)d_in[15];
  const float* val_b1 = (const float*)d_in[16];
  const float* val_w2 = (const float*)d_in[17];
  const float* val_b2 = (const float*)d_in[18];
  float* out = (float*)d_out;

  const int n = in_sizes[0] / FD;           // 100000
  const int e = in_sizes[1] / 2;            // 1600000
  const int L = in_sizes[7] / (HD * HD);    // 3
  const int G = out_size / 4;               // 64

  // workspace carve
  char* p = (char*)d_ws;
  auto carve = [&](size_t bytes) {
    void* r = (void*)p;
    p += (bytes + 255) & ~(size_t)255;
    return r;
  };
  ushort* x       = (ushort*)carve((size_t)n * HD * 2);    // bf16 x
  uchar*  xw8     = (uchar*)carve((size_t)n * HD);         // fp8 message rows
  uint*   pairs   = (uint*)carve((size_t)e * 4);           // bucketed (src,dst) pairs
  float*  dinv    = (float*)carve((size_t)n * 4);
  int*    offs    = (int*)carve((size_t)(n + 1) * 4);
  int*    csr_src = (int*)carve((size_t)e * 4);
  int*    startg  = (int*)carve((size_t)(G + 1) * 4);
  float*  psum    = (float*)carve((size_t)G * PCH * HD * 4);
  float*  pmax    = (float*)carve((size_t)G * PCH * HD * 4);
  const int nbk   = (n + (1 << BKT_SHIFT) - 1) >> BKT_SHIFT;   // 391 buckets
  int*    bucket_count  = (int*)carve((size_t)nbk * 4);
  int*    bucket_base   = (int*)carve((size_t)(nbk + 1) * 4);
  int*    bucket_cursor = (int*)carve((size_t)nbk * 4);
  ushort* wt_e1   = (ushort*)carve((size_t)128 * FD * 2);      // enc_w1^T bf16
  ushort* wt_e2   = (ushort*)carve((size_t)128 * HD * 2);      // enc_w2^T bf16
  ushort* wt_g    = (ushort*)carve((size_t)3 * 128 * HD * 2);  // gcn_w^T bf16

  const int ntiles = (n + 63) / 64;
  const int ebk_grid = (e + EPB - 1) / EPB;
  const int gemm_grid = 768;   // 3 blocks/CU, ~2 tiles each

  // ---- graph structure ----
  zero_int_kernel<<<(nbk + 255) / 256, 256, 0, stream>>>(bucket_count, nbk);
  bucket_count_kernel<<<ebk_grid, 256, 0, stream>>>(ei + e, bucket_count, e, nbk);
  bucket_scan_kernel<<<1, 512, 0, stream>>>(bucket_count, bucket_base, bucket_cursor, nbk);
  bucket_fill_kernel<<<ebk_grid, 256, 0, stream>>>(ei, ei + e, bucket_cursor, pairs, e, nbk);
  bucket_scatter_kernel<<<nbk, 256, 0, stream>>>(pairs, bucket_base, offs, dinv, csr_src, n, nbk);

  // ---- weight transposes (one kernel) ----
  {
    int tot = 128 * FD + 128 * HD + L * 128 * HD;
    convert_all_wt_kernel<<<(tot + 255) / 256, 256, 0, stream>>>(
        enc_w1, enc_w2, gcn_w, wt_e1, wt_e2, wt_g, L);
  }

  // ---- fused encoder ----
  encoder_fused_kernel<<<ntiles, 256, 0, stream>>>(
      nf, wt_e1, enc_b1, wt_e2, enc_b2, x, n);

  // ---- GCN layers: GEMM writes fp8 rows pre-scaled by dinv*16 ----
  for (int l = 0; l < L; ++l) {
    mfma_gemm_fp8_kernel<<<gemm_grid, 256, 0, stream>>>(
        x, wt_g + (size_t)l * 128 * HD, xw8, dinv, n, ntiles);
    agg_update_kernel<<<(n + 3) / 4, 256, 0, stream>>>(
        xw8, x, csr_src, offs, dinv, gcn_b + (size_t)l * HD, n);
  }

  // ---- pooling + heads ----
  bounds_kernel<<<(n + 1 + 255) / 256, 256, 0, stream>>>(batch, startg, n, G);
  pool_partial_kernel<<<G * PCH, 256, 0, stream>>>(x, startg, psum, pmax);
  heads_kernel<<<G, 128, 0, stream>>>(psum, pmax, startg,
      dec_w1, dec_b1, dec_w2, dec_b2, dec_w3, dec_b3,
      val_w1, val_b1, val_w2, val_b2, out, G);
}

// Round 13
// 330.074 us; speedup vs baseline: 1.1997x; 1.0902x over previous
//
#include <hip/hip_runtime.h>
#include <math.h>

constexpr int HD = 128;   // hidden dim
constexpr int FD = 64;    // input feature dim
constexpr int PCH = 32;   // pooling chunks per graph
constexpr int BKT_SHIFT = 8;           // 256 nodes per bucket
constexpr int EPB = 4096;              // edges per block in bucket passes
constexpr float FP8_SCALE = 16.f;      // pre-scale before e4m3 quantization
constexpr float FP8_INV_SCALE = 1.f / 16.f;

typedef unsigned int uint;
typedef unsigned short ushort;
typedef unsigned char uchar;

using bf16x8 = __attribute__((ext_vector_type(8))) short;   // 4 VGPRs
using f32x4  = __attribute__((ext_vector_type(4))) float;

#if defined(__has_builtin)
#if __has_builtin(__builtin_amdgcn_cvt_pk_f32_fp8) && __has_builtin(__builtin_amdgcn_cvt_pk_fp8_f32)
#define HW_FP8 1
#endif
#endif

static __device__ inline ushort f2bf(float f) {   // round-to-nearest-even bf16
  uint u = __float_as_uint(f);
  return (ushort)((u + 0x7fffu + ((u >> 16) & 1u)) >> 16);
}
static __device__ inline float bf2f(ushort b) {
  return __uint_as_float((uint)b << 16);
}
static __device__ inline uint pack2bf(float a, float b) {
  return (uint)f2bf(a) | ((uint)f2bf(b) << 16);
}

// ---- fp8 e4m3 (OCP) helpers: HW path + fallback ----
static __device__ inline uchar enc_fp8_byte(float f) {
#ifdef HW_FP8
  return (uchar)(__builtin_amdgcn_cvt_pk_fp8_f32(f, f, 0, false) & 0xff);
#else
  float a = fabsf(f);
  uint s = (f < 0.f) ? 0x80u : 0u;
  if (!(a > 0.f)) return (uchar)s;
  a = fminf(a, 448.f);
  uint b = __float_as_uint(a);
  int e = (int)(b >> 23) - 127;
  if (e < -6) {                       // denormal domain: multiples of 2^-9
    int q = (int)rintf(a * 512.f);
    if (q <= 0) return (uchar)s;
    if (q >= 8) return (uchar)(s | 0x08u);
    return (uchar)(s | (uint)q);
  }
  uint r = b + 0x7ffffu + ((b >> 20) & 1u);   // RTN-even at mantissa bit 20
  uint m = (r >> 20) & 7u;
  int ee = (int)(r >> 23) - 127 + 7;
  if (ee <= 0) return (uchar)(s | 0x08u);
  if (ee > 15) return (uchar)(s | 0x7eu);
  return (uchar)(s | ((uint)ee << 3) | m);
#endif
}

static __device__ inline float dec_fp8_byte(uint em_s) {   // fallback scalar decode
  uint s = (em_s & 0x80u) << 24;
  uint em = em_s & 0x7fu;
  float v;
  if (em < 8) v = (float)em * (1.f / 512.f);
  else v = __uint_as_float((em + (120u << 3)) << 20);
  return __uint_as_float(__float_as_uint(v) | s);
}

static __device__ inline void dec_fp8x4(uint u, float* dst) {
#ifdef HW_FP8
  auto a = __builtin_amdgcn_cvt_pk_f32_fp8((int)u, false);
  auto b = __builtin_amdgcn_cvt_pk_f32_fp8((int)u, true);
  dst[0] = a[0]; dst[1] = a[1]; dst[2] = b[0]; dst[3] = b[1];
#else
  dst[0] = dec_fp8_byte(u & 0xffu);
  dst[1] = dec_fp8_byte((u >> 8) & 0xffu);
  dst[2] = dec_fp8_byte((u >> 16) & 0xffu);
  dst[3] = dec_fp8_byte(u >> 24);
#endif
}

// ---------------- bucketed CSR build (also produces offs, dinv) ----------------
__global__ __launch_bounds__(256) void bucket_count_kernel(const int* __restrict__ dst,
    int* __restrict__ bucket_count, int e, int nbk) {
  __shared__ int hist[512];
  int t = threadIdx.x;
  for (int i = t; i < nbk; i += 256) hist[i] = 0;
  __syncthreads();
  int lo = blockIdx.x * EPB;
  int hi = lo + EPB; if (hi > e) hi = e;
  for (int i = lo + t; i < hi; i += 256) atomicAdd(&hist[dst[i] >> BKT_SHIFT], 1);
  __syncthreads();
  for (int i = t; i < nbk; i += 256) {
    int c = hist[i];
    if (c) atomicAdd(&bucket_count[i], c);
  }
}

__global__ __launch_bounds__(512) void bucket_scan_kernel(const int* __restrict__ bucket_count,
    int* __restrict__ bucket_base, int* __restrict__ bucket_cursor, int nbk) {
  __shared__ int sh[512];
  int t = threadIdx.x;
  int v = (t < nbk) ? bucket_count[t] : 0;
  sh[t] = v;
  __syncthreads();
  for (int d = 1; d < 512; d <<= 1) {
    int u = (t >= d) ? sh[t - d] : 0;
    __syncthreads();
    sh[t] += u;
    __syncthreads();
  }
  if (t < nbk) {
    int ex = sh[t] - v;
    bucket_base[t] = ex;
    bucket_cursor[t] = ex;
  }
  if (t == 511) bucket_base[nbk] = sh[511];
}

// pairs packed: (src << 8) | (dst & 255); src < 2^17, bucket-local dst < 256
__global__ __launch_bounds__(256) void bucket_fill_kernel(const int* __restrict__ src,
    const int* __restrict__ dst, int* __restrict__ bucket_cursor,
    uint* __restrict__ pairs, int e, int nbk) {
  __shared__ int hist[512];
  int t = threadIdx.x;
  for (int i = t; i < nbk; i += 256) hist[i] = 0;
  __syncthreads();
  int lo = blockIdx.x * EPB;
  int hi = lo + EPB; if (hi > e) hi = e;
  for (int i = lo + t; i < hi; i += 256) atomicAdd(&hist[dst[i] >> BKT_SHIFT], 1);
  __syncthreads();
  for (int i = t; i < nbk; i += 256) {
    int c = hist[i];
    hist[i] = c ? atomicAdd(&bucket_cursor[i], c) : 0;   // hist now = write cursor
  }
  __syncthreads();
  for (int i = lo + t; i < hi; i += 256) {
    int s = src[i], d = dst[i];
    int pos = atomicAdd(&hist[d >> BKT_SHIFT], 1);
    pairs[pos] = ((uint)s << 8) | (uint)(d & 255);
  }
}

// one block per bucket: count per-node in LDS, scan -> offs & dinv, then scatter
__global__ __launch_bounds__(256) void bucket_scatter_kernel(const uint* __restrict__ pairs,
    const int* __restrict__ bucket_base, int* __restrict__ offs,
    float* __restrict__ dinv, int* __restrict__ csr_src, int n, int nbk) {
  __shared__ int cnt[256];
  __shared__ int pre[256];
  int b = blockIdx.x, t = threadIdx.x;
  int node0 = b << BKT_SHIFT;
  bool valid_node = (node0 + t) < n;
  cnt[t] = 0;
  __syncthreads();
  int lo = bucket_base[b], hi = bucket_base[b + 1];
  for (int i = lo + t; i < hi; i += 256)
    atomicAdd(&cnt[pairs[i] & 255u], 1);
  __syncthreads();
  int v = cnt[t];
  pre[t] = v;
  __syncthreads();
  for (int d = 1; d < 256; d <<= 1) {
    int u = (t >= d) ? pre[t - d] : 0;
    __syncthreads();
    pre[t] += u;
    __syncthreads();
  }
  int off = lo + pre[t] - v;   // exclusive prefix within bucket + bucket base
  if (valid_node) {
    offs[node0 + t] = off;
    dinv[node0 + t] = rsqrtf((float)(v + 1));   // +1: self-loop
  }
  __syncthreads();
  cnt[t] = off;   // reuse as cursor
  __syncthreads();
  for (int i = lo + t; i < hi; i += 256) {
    uint pp = pairs[i];
    int pos = atomicAdd(&cnt[pp & 255u], 1);
    csr_src[pos] = (int)(pp >> 8);
  }
  if (b == 0 && t == 0) offs[n] = bucket_base[nbk];
}

// ---------------- all weight transposes fused: wt[c][k] = bf16(W[k][c]) ------------
__global__ void convert_all_wt_kernel(const float* __restrict__ enc_w1,
    const float* __restrict__ enc_w2, const float* __restrict__ gcn_w,
    ushort* __restrict__ wt_e1, ushort* __restrict__ wt_e2, ushort* __restrict__ wt_g,
    int L) {
  const int S0 = 128 * FD, S1 = 128 * HD;
  int i = blockIdx.x * 256 + threadIdx.x;
  if (i < S0) {
    int c = i / FD, k = i - c * FD;
    wt_e1[i] = f2bf(enc_w1[k * 128 + c]);
  } else if (i < S0 + S1) {
    int j = i - S0;
    int c = j / HD, k = j - c * HD;
    wt_e2[j] = f2bf(enc_w2[k * 128 + c]);
  } else if (i < S0 + S1 + L * S1) {
    int j = i - S0 - S1;
    int l = j / S1, jj = j - l * S1;
    int c = jj / HD, k = jj - c * HD;
    wt_g[(size_t)l * S1 + jj] = f2bf(gcn_w[(size_t)l * HD * HD + k * 128 + c]);
  }
}

// ---------------- fused encoder: x = relu(nf@W1+b1)@W2 + b2  (bf16 out) -----------
// LDS-packed epilogue: bf16 results staged linear in Mid, then coalesced uint4 out.
__global__ __launch_bounds__(256) void encoder_fused_kernel(
    const float* __restrict__ nf, const ushort* __restrict__ wt1,
    const float* __restrict__ b1, const ushort* __restrict__ wt2,
    const float* __restrict__ b2, ushort* __restrict__ xout, int M) {
  __shared__ ushort As[64 * FD];     // 8 KB
  __shared__ ushort W1s[128 * FD];   // 16 KB
  __shared__ ushort Mid[64 * HD];    // 16 KB (GEMM1 out swizzled; reused linear for epilogue)
  __shared__ ushort W2s[128 * HD];   // 32 KB
  const int tid = threadIdx.x;
  const int r0 = blockIdx.x * 64;

  // stage A (f32 -> bf16), swizzled
  {
    constexpr int C4 = FD / 4;
    const float4* A4 = (const float4*)nf;
    #pragma unroll
    for (int i = tid; i < 64 * C4; i += 256) {
      int r = i / C4, c4 = i - r * C4;
      int row = r0 + r;
      float4 v = make_float4(0.f, 0.f, 0.f, 0.f);
      if (row < M) v = A4[(size_t)row * C4 + c4];
      ushort4 u;
      u.x = f2bf(v.x); u.y = f2bf(v.y); u.z = f2bf(v.z); u.w = f2bf(v.w);
      int elem = (r * FD + c4 * 4) ^ ((r & 7) << 3);
      *(ushort4*)&As[elem] = u;
    }
  }
  // stage W1t [128][64], swizzled
  {
    constexpr int C8 = FD / 8;
    const uint4* W4 = (const uint4*)wt1;
    #pragma unroll
    for (int i = tid; i < 128 * C8; i += 256) {
      int c = i / C8, k8 = i - c * C8;
      uint4 v = W4[i];
      int elem = (c * FD + k8 * 8) ^ ((c & 7) << 3);
      *(uint4*)&W1s[elem] = v;
    }
  }
  // stage W2t [128][128], swizzled
  {
    constexpr int C8 = HD / 8;
    const uint4* W4 = (const uint4*)wt2;
    #pragma unroll
    for (int i = tid; i < 128 * C8; i += 256) {
      int c = i / C8, k8 = i - c * C8;
      uint4 v = W4[i];
      int elem = (c * HD + k8 * 8) ^ ((c & 7) << 3);
      *(uint4*)&W2s[elem] = v;
    }
  }
  __syncthreads();

  const int l = tid & 63;
  const int wid = tid >> 6;
  const int lr = l & 15;
  const int lk = l >> 4;
  const int wr = wid * 16;

  // ---- GEMM1: Mid = relu(A @ W1 + b1), swizzled ----
  {
    f32x4 acc[8];
    #pragma unroll
    for (int cb = 0; cb < 8; ++cb) acc[cb] = (f32x4){0.f, 0.f, 0.f, 0.f};
    #pragma unroll
    for (int kc = 0; kc < FD / 32; ++kc) {
      int ar = wr + lr;
      bf16x8 af = *(const bf16x8*)&As[(ar * FD + kc * 32 + lk * 8) ^ ((ar & 7) << 3)];
      #pragma unroll
      for (int cb = 0; cb < 8; ++cb) {
        int col = cb * 16 + lr;
        bf16x8 bfr = *(const bf16x8*)&W1s[(col * FD + kc * 32 + lk * 8) ^ ((col & 7) << 3)];
        acc[cb] = __builtin_amdgcn_mfma_f32_16x16x32_bf16(af, bfr, acc[cb], 0, 0, 0);
      }
    }
    #pragma unroll
    for (int cb = 0; cb < 8; ++cb) {
      int col = cb * 16 + lr;
      float bb = b1[col];
      #pragma unroll
      for (int j = 0; j < 4; ++j) {
        int row = wr + lk * 4 + j;
        float o = fmaxf(acc[cb][j] + bb, 0.f);
        Mid[(row * HD + col) ^ ((row & 7) << 3)] = f2bf(o);
      }
    }
  }
  __syncthreads();

  // ---- GEMM2: x = Mid @ W2 + b2 ----
  f32x4 acc[8];
  #pragma unroll
  for (int cb = 0; cb < 8; ++cb) acc[cb] = (f32x4){0.f, 0.f, 0.f, 0.f};
  #pragma unroll
  for (int kc = 0; kc < HD / 32; ++kc) {
    int ar = wr + lr;
    bf16x8 af = *(const bf16x8*)&Mid[(ar * HD + kc * 32 + lk * 8) ^ ((ar & 7) << 3)];
    #pragma unroll
    for (int cb = 0; cb < 8; ++cb) {
      int col = cb * 16 + lr;
      bf16x8 bfr = *(const bf16x8*)&W2s[(col * HD + kc * 32 + lk * 8) ^ ((col & 7) << 3)];
      acc[cb] = __builtin_amdgcn_mfma_f32_16x16x32_bf16(af, bfr, acc[cb], 0, 0, 0);
    }
  }
  __syncthreads();   // all Mid readers done; reuse Mid linear as epilogue buffer
  #pragma unroll
  for (int cb = 0; cb < 8; ++cb) {
    int col = cb * 16 + lr;
    float bb = b2[col];
    #pragma unroll
    for (int j = 0; j < 4; ++j) {
      int row = wr + lk * 4 + j;
      Mid[row * HD + col] = f2bf(acc[cb][j] + bb);
    }
  }
  __syncthreads();
  // coalesced write: 64 rows x 16 uint4 = 1024 uint4
  {
    const uint4* Ms4 = (const uint4*)Mid;
    uint4* O4 = (uint4*)xout;
    #pragma unroll
    for (int k = 0; k < 4; ++k) {
      int i = tid + k * 256;
      int row = i >> 4;   // 16 uint4 per row
      if (r0 + row < M) O4[((size_t)r0 + row) * 16 + (i & 15)] = Ms4[i];
    }
  }
}

// ---------------- multi-tile MFMA GEMM (GCN layers): fp8 out, dinv*16 folded ------
// Wt staged once per block; grid-stride loop over 64-row tiles.
// LDS-packed epilogue: fp8 bytes staged linear in As, then coalesced uint4 out.
__global__ __launch_bounds__(256) void mfma_gemm_fp8_kernel(const ushort* __restrict__ A,
    const ushort* __restrict__ Wt, uchar* __restrict__ Cout,
    const float* __restrict__ dinv, int M, int ntiles) {
  __shared__ ushort As[64 * HD];    // 16 KB (stage swizzled; reused as 8KB fp8 epilogue buf)
  __shared__ ushort Ws[128 * HD];   // 32 KB
  const int tid = threadIdx.x;

  // stage Wt once
  {
    constexpr int C8 = HD / 8;
    const uint4* W4 = (const uint4*)Wt;
    #pragma unroll
    for (int i = tid; i < 128 * C8; i += 256) {
      int c = i / C8, k8 = i - c * C8;
      uint4 v = W4[i];
      int elem = (c * HD + k8 * 8) ^ ((c & 7) << 3);
      *(uint4*)&Ws[elem] = v;
    }
  }

  const int l = tid & 63;
  const int wid = tid >> 6;
  const int lr = l & 15;
  const int lk = l >> 4;
  const int wr = wid * 16;

  for (int tile = blockIdx.x; tile < ntiles; tile += gridDim.x) {
    __syncthreads();   // Ws ready / prior-tile epilogue readers done
    const int r0 = tile * 64;
    {
      constexpr int C8 = HD / 8;
      const uint4* A4 = (const uint4*)A;
      #pragma unroll
      for (int i = tid; i < 64 * C8; i += 256) {
        int r = i / C8, c8 = i - r * C8;
        int row = r0 + r;
        uint4 v = make_uint4(0u, 0u, 0u, 0u);
        if (row < M) v = A4[(size_t)row * C8 + c8];
        int elem = (r * HD + c8 * 8) ^ ((r & 7) << 3);
        *(uint4*)&As[elem] = v;
      }
    }
    __syncthreads();

    f32x4 acc[8];
    #pragma unroll
    for (int cb = 0; cb < 8; ++cb) acc[cb] = (f32x4){0.f, 0.f, 0.f, 0.f};
    #pragma unroll
    for (int kc = 0; kc < HD / 32; ++kc) {
      int ar = wr + lr;
      bf16x8 af = *(const bf16x8*)&As[(ar * HD + kc * 32 + lk * 8) ^ ((ar & 7) << 3)];
      #pragma unroll
      for (int cb = 0; cb < 8; ++cb) {
        int col = cb * 16 + lr;
        bf16x8 bfr = *(const bf16x8*)&Ws[(col * HD + kc * 32 + lk * 8) ^ ((col & 7) << 3)];
        acc[cb] = __builtin_amdgcn_mfma_f32_16x16x32_bf16(af, bfr, acc[cb], 0, 0, 0);
      }
    }
    __syncthreads();   // all As readers done; reuse As as fp8 epilogue buffer

    uchar* Cs = (uchar*)As;   // 64 x 128 bytes, linear
    float dv[4];
    #pragma unroll
    for (int j = 0; j < 4; ++j) {
      int row = r0 + wr + lk * 4 + j;
      dv[j] = (row < M) ? dinv[row] * FP8_SCALE : 0.f;
    }
    #pragma unroll
    for (int cb = 0; cb < 8; ++cb) {
      int col = cb * 16 + lr;
      #pragma unroll
      for (int j = 0; j < 4; ++j) {
        int row = wr + lk * 4 + j;
        Cs[row * 128 + col] = enc_fp8_byte(acc[cb][j] * dv[j]);
      }
    }
    __syncthreads();
    // coalesced write: 64 rows x 8 uint4 = 512 uint4
    {
      const uint4* Cs4 = (const uint4*)Cs;
      uint4* O4 = (uint4*)Cout;
      #pragma unroll
      for (int k = 0; k < 2; ++k) {
        int i = tid + k * 256;
        int row = i >> 3;   // 8 uint4 per row
        if (r0 + row < M) O4[((size_t)r0 + row) * 8 + (i & 7)] = Cs4[i];
      }
    }
  }
}

// ---------------- GCN aggregation + residual update (round-9 layout, unchanged) ----
__global__ __launch_bounds__(256) void agg_update_kernel(
    const uchar* __restrict__ xws, ushort* __restrict__ x,
    const int* __restrict__ csr_src, const int* __restrict__ offs,
    const float* __restrict__ dinv, const float* __restrict__ bias, int n) {
  int node = blockIdx.x * 4 + (threadIdx.x >> 6);
  if (node >= n) return;
  int lane = threadIdx.x & 63;
  int grp = lane >> 4;       // edge group 0..3
  int cl = lane & 15;        // row chunk: dims 8*cl .. 8*cl+7
  const uint2* xw2 = (const uint2*)xws;   // row = 16 uint2 (128 fp8)
  float acc[8];
  #pragma unroll
  for (int k = 0; k < 8; ++k) acc[k] = 0.f;

  auto add_row = [&](uint2 v) {
    float f[4];
    dec_fp8x4(v.x, f);
    acc[0] += f[0]; acc[1] += f[1]; acc[2] += f[2]; acc[3] += f[3];
    dec_fp8x4(v.y, f);
    acc[4] += f[0]; acc[5] += f[1]; acc[6] += f[2]; acc[7] += f[3];
  };

  int beg = offs[node], end = offs[node + 1];
  int j = beg + grp;
  for (; j + 12 < end; j += 16) {
    int s0 = csr_src[j];
    int s1 = csr_src[j + 4];
    int s2 = csr_src[j + 8];
    int s3 = csr_src[j + 12];
    uint2 v0 = xw2[(size_t)s0 * 16 + cl];
    uint2 v1 = xw2[(size_t)s1 * 16 + cl];
    uint2 v2 = xw2[(size_t)s2 * 16 + cl];
    uint2 v3 = xw2[(size_t)s3 * 16 + cl];
    add_row(v0); add_row(v1); add_row(v2); add_row(v3);
  }
  for (; j + 4 < end; j += 8) {
    int s0 = csr_src[j];
    int s1 = csr_src[j + 4];
    uint2 v0 = xw2[(size_t)s0 * 16 + cl];
    uint2 v1 = xw2[(size_t)s1 * 16 + cl];
    add_row(v0); add_row(v1);
  }
  if (j < end) {
    uint2 v0 = xw2[(size_t)csr_src[j] * 16 + cl];
    add_row(v0);
  }
  if (grp == 0) {   // self-loop term
    uint2 vi = xw2[(size_t)node * 16 + cl];
    add_row(vi);
  }
  #pragma unroll
  for (int k = 0; k < 8; ++k) {
    acc[k] += __shfl_xor(acc[k], 16);
    acc[k] += __shfl_xor(acc[k], 32);
  }
  if (grp == 0) {
    float di = dinv[node] * FP8_INV_SCALE;
    const float4* b4 = (const float4*)bias;
    float4 bb0 = b4[cl * 2], bb1 = b4[cl * 2 + 1];
    float bbv[8] = {bb0.x, bb0.y, bb0.z, bb0.w, bb1.x, bb1.y, bb1.z, bb1.w};
    uint4* xv4 = (uint4*)x;
    size_t xi = (size_t)node * 16 + cl;
    uint4 xv = xv4[xi];
    uint xu[4] = {xv.x, xv.y, xv.z, xv.w};
    float o[8];
    #pragma unroll
    for (int q = 0; q < 4; ++q) {
      float lo = __uint_as_float(xu[q] << 16);
      float hi = __uint_as_float(xu[q] & 0xffff0000u);
      o[2 * q]     = fmaxf(fmaf(acc[2 * q],     di, bbv[2 * q]),     0.f) + lo;
      o[2 * q + 1] = fmaxf(fmaf(acc[2 * q + 1], di, bbv[2 * q + 1]), 0.f) + hi;
    }
    uint4 ou;
    ou.x = pack2bf(o[0], o[1]);
    ou.y = pack2bf(o[2], o[3]);
    ou.z = pack2bf(o[4], o[5]);
    ou.w = pack2bf(o[6], o[7]);
    xv4[xi] = ou;
  }
}

// ---------------- graph boundaries from sorted batch ----------------
__global__ void bounds_kernel(const int* __restrict__ batch, int* __restrict__ startg,
                              int n, int ng) {
  int i = blockIdx.x * blockDim.x + threadIdx.x;
  if (i > n) return;
  int bi = (i < n) ? batch[i] : ng;
  int bp = (i == 0) ? -1 : batch[i - 1];
  for (int g = bp + 1; g <= bi && g <= ng; ++g) startg[g] = i;
}

// ---------------- per-graph mean/max pooling: partial stage, vectorized ----------------
__global__ __launch_bounds__(256) void pool_partial_kernel(const ushort* __restrict__ x,
    const int* __restrict__ startg, float* __restrict__ psum, float* __restrict__ pmax) {
  __shared__ float ssum[16][128];
  __shared__ float smax[16][128];
  int g = blockIdx.x / PCH, ch = blockIdx.x % PCH;
  int t = threadIdx.x;
  int rg = t >> 4, cg = t & 15;
  int s0 = startg[g], s1 = startg[g + 1];
  int cnt = s1 - s0;
  int len = (cnt + PCH - 1) / PCH;
  int lo = s0 + ch * len;
  int hi = lo + len; if (hi > s1) hi = s1;
  float sum[8], mx[8];
  #pragma unroll
  for (int k = 0; k < 8; ++k) { sum[k] = 0.f; mx[k] = -INFINITY; }
  const uint4* x4 = (const uint4*)x;
  for (int r = lo + rg; r < hi; r += 16) {
    uint4 v = x4[(size_t)r * 16 + cg];
    uint uu[4] = {v.x, v.y, v.z, v.w};
    #pragma unroll
    for (int q = 0; q < 4; ++q) {
      float a = __uint_as_float(uu[q] << 16);
      float b = __uint_as_float(uu[q] & 0xffff0000u);
      sum[2 * q] += a;     mx[2 * q]     = fmaxf(mx[2 * q], a);
      sum[2 * q + 1] += b; mx[2 * q + 1] = fmaxf(mx[2 * q + 1], b);
    }
  }
  #pragma unroll
  for (int k = 0; k < 8; ++k) {
    ssum[rg][cg * 8 + k] = sum[k];
    smax[rg][cg * 8 + k] = mx[k];
  }
  __syncthreads();
  #pragma unroll
  for (int d = 8; d > 0; d >>= 1) {
    if (rg < d) {
      #pragma unroll
      for (int k = 0; k < 8; ++k) {
        int c = cg * 8 + k;
        ssum[rg][c] += ssum[rg + d][c];
        smax[rg][c] = fmaxf(smax[rg][c], smax[rg + d][c]);
      }
    }
    __syncthreads();
  }
  if (rg == 0) {
    #pragma unroll
    for (int k = 0; k < 8; ++k) {
      int c = cg * 8 + k;
      psum[(size_t)blockIdx.x * HD + c] = ssum[0][c];
      pmax[(size_t)blockIdx.x * HD + c] = smax[0][c];
    }
  }
}

// ---------------- pool-final + decoder + value heads (one block per graph) ----------
__global__ __launch_bounds__(128) void heads_kernel(
    const float* __restrict__ psum, const float* __restrict__ pmax,
    const int* __restrict__ startg,
    const float* __restrict__ dw1, const float* __restrict__ db1,
    const float* __restrict__ dw2, const float* __restrict__ db2,
    const float* __restrict__ dw3, const float* __restrict__ db3,
    const float* __restrict__ vw1, const float* __restrict__ vb1,
    const float* __restrict__ vw2, const float* __restrict__ vb2,
    float* __restrict__ out, int ng) {
  __shared__ float rep[256];
  __shared__ float h1[128];
  __shared__ float h2[64];
  __shared__ float v1[128];
  int g = blockIdx.x, t = threadIdx.x;
  {
    float sum = 0.f, mx = -INFINITY;
    #pragma unroll
    for (int ch = 0; ch < PCH; ++ch) {
      sum += psum[(size_t)(g * PCH + ch) * HD + t];
      mx = fmaxf(mx, pmax[(size_t)(g * PCH + ch) * HD + t]);
    }
    int cnt = startg[g + 1] - startg[g];
    float denom = (float)(cnt > 0 ? cnt : 1);
    rep[t] = sum / denom;
    rep[128 + t] = mx;
  }
  __syncthreads();
  float a = db1[t], b = vb1[t];
  for (int k = 0; k < 256; ++k) {
    float rv = rep[k];
    a = fmaf(rv, dw1[k * 128 + t], a);
    b = fmaf(rv, vw1[k * 128 + t], b);
  }
  h1[t] = fmaxf(a, 0.f);
  v1[t] = fmaxf(b, 0.f);
  __syncthreads();
  if (t < 64) {
    float c = db2[t];
    for (int k = 0; k < 128; ++k) c = fmaf(h1[k], dw2[k * 64 + t], c);
    h2[t] = fmaxf(c, 0.f);
  }
  __syncthreads();
  if (t == 0) {
    float l0 = db3[0], l2 = db3[2];
    for (int k = 0; k < 64; ++k) {
      l0 = fmaf(h2[k], dw3[k * 3 + 0], l0);
      l2 = fmaf(h2[k], dw3[k * 3 + 2], l2);
    }
    out[g] = 1.f / (1.f + expf(-l0));          // adaptation_prob
    out[ng + g] = 1.0f;                        // softmax over 1 element == 1
    out[2 * ng + g] = 1.f / (1.f + expf(-l2)); // urgency_score
    float v = vb2[0];
    for (int k = 0; k < 128; ++k) v = fmaf(v1[k], vw2[k], v);
    out[3 * ng + g] = v;                       // value_estimate
  }
}

// ---------------- launch ----------------
extern "C" void kernel_launch(void* const* d_in, const int* in_sizes, int n_in,
                              void* d_out, int out_size, void* d_ws, size_t ws_size,
                              hipStream_t stream) {
  const float* nf     = (const float*)d_in[0];
  const int*   ei     = (const int*)d_in[1];
  const int*   batch  = (const int*)d_in[2];
  const float* enc_w1 = (const float*)d_in[3];
  const float* enc_b1 = (const float*)d_in[4];
  const float* enc_w2 = (const float*)d_in[5];
  const float* enc_b2 = (const float*)d_in[6];
  const float* gcn_w  = (const float*)d_in[7];
  const float* gcn_b  = (const float*)d_in[8];
  const float* dec_w1 = (const float*)d_in[9];
  const float* dec_b1 = (const float*)d_in[10];
  const float* dec_w2 = (const float*)d_in[11];
  const float* dec_b2 = (const float*)d_in[12];
  const float* dec_w3 = (const float*)d_in[13];
  const float* dec_b3 = (const float*)d_in[14];
  const float* val_w1 = (const float*)d_in[15];
  const float* val_b1 = (const float*)d_in[16];
  const float* val_w2 = (const float*)d_in[17];
  const float* val_b2 = (const float*)d_in[18];
  float* out = (float*)d_out;

  const int n = in_sizes[0] / FD;           // 100000
  const int e = in_sizes[1] / 2;            // 1600000
  const int L = in_sizes[7] / (HD * HD);    // 3
  const int G = out_size / 4;               // 64

  // workspace carve
  char* p = (char*)d_ws;
  auto carve = [&](size_t bytes) {
    void* r = (void*)p;
    p += (bytes + 255) & ~(size_t)255;
    return r;
  };
  ushort* x       = (ushort*)carve((size_t)n * HD * 2);    // bf16 x
  uchar*  xw8     = (uchar*)carve((size_t)n * HD);         // fp8 message rows
  uint*   pairs   = (uint*)carve((size_t)e * 4);           // bucketed (src,dst) pairs
  float*  dinv    = (float*)carve((size_t)n * 4);
  int*    offs    = (int*)carve((size_t)(n + 1) * 4);
  int*    csr_src = (int*)carve((size_t)e * 4);
  int*    startg  = (int*)carve((size_t)(G + 1) * 4);
  float*  psum    = (float*)carve((size_t)G * PCH * HD * 4);
  float*  pmax    = (float*)carve((size_t)G * PCH * HD * 4);
  const int nbk   = (n + (1 << BKT_SHIFT) - 1) >> BKT_SHIFT;   // 391 buckets
  int*    bucket_count  = (int*)carve((size_t)nbk * 4);
  int*    bucket_base   = (int*)carve((size_t)(nbk + 1) * 4);
  int*    bucket_cursor = (int*)carve((size_t)nbk * 4);
  ushort* wt_e1   = (ushort*)carve((size_t)128 * FD * 2);      // enc_w1^T bf16
  ushort* wt_e2   = (ushort*)carve((size_t)128 * HD * 2);      // enc_w2^T bf16
  ushort* wt_g    = (ushort*)carve((size_t)3 * 128 * HD * 2);  // gcn_w^T bf16

  const int ntiles = (n + 63) / 64;
  const int ebk_grid = (e + EPB - 1) / EPB;
  const int gemm_grid = 768;   // 3 blocks/CU, ~2 tiles each

  // ---- graph structure ----
  hipMemsetAsync(bucket_count, 0, (size_t)nbk * 4, stream);
  bucket_count_kernel<<<ebk_grid, 256, 0, stream>>>(ei + e, bucket_count, e, nbk);
  bucket_scan_kernel<<<1, 512, 0, stream>>>(bucket_count, bucket_base, bucket_cursor, nbk);
  bucket_fill_kernel<<<ebk_grid, 256, 0, stream>>>(ei, ei + e, bucket_cursor, pairs, e, nbk);
  bucket_scatter_kernel<<<nbk, 256, 0, stream>>>(pairs, bucket_base, offs, dinv, csr_src, n, nbk);

  // ---- weight transposes (one kernel) ----
  {
    int tot = 128 * FD + 128 * HD + L * 128 * HD;
    convert_all_wt_kernel<<<(tot + 255) / 256, 256, 0, stream>>>(
        enc_w1, enc_w2, gcn_w, wt_e1, wt_e2, wt_g, L);
  }

  // ---- fused encoder ----
  encoder_fused_kernel<<<ntiles, 256, 0, stream>>>(
      nf, wt_e1, enc_b1, wt_e2, enc_b2, x, n);

  // ---- GCN layers: GEMM writes fp8 rows pre-scaled by dinv*16 ----
  for (int l = 0; l < L; ++l) {
    mfma_gemm_fp8_kernel<<<gemm_grid, 256, 0, stream>>>(
        x, wt_g + (size_t)l * 128 * HD, xw8, dinv, n, ntiles);
    agg_update_kernel<<<(n + 3) / 4, 256, 0, stream>>>(
        xw8, x, csr_src, offs, dinv, gcn_b + (size_t)l * HD, n);
  }

  // ---- pooling + heads ----
  bounds_kernel<<<(n + 1 + 255) / 256, 256, 0, stream>>>(batch, startg, n, G);
  pool_partial_kernel<<<G * PCH, 256, 0, stream>>>(x, startg, psum, pmax);
  heads_kernel<<<G, 128, 0, stream>>>(psum, pmax, startg,
      dec_w1, dec_b1, dec_w2, dec_b2, dec_w3, dec_b3,
      val_w1, val_b1, val_w2, val_b2, out, G);
}

// Round 14
// 321.903 us; speedup vs baseline: 1.2301x; 1.0254x over previous
//
#include <hip/hip_runtime.h>
#include <math.h>

constexpr int HD = 128;   // hidden dim
constexpr int FD = 64;    // input feature dim
constexpr int PCH = 32;   // pooling chunks per graph
constexpr int BKT_SHIFT = 8;           // 256 nodes per bucket
constexpr int BKT_CAP = 6144;          // padded slots per bucket (avg 4092, +6 sigma safe)
constexpr int EPB = 4096;              // edges per block in bucket fill
constexpr float FP8_SCALE = 16.f;      // pre-scale before e4m3 quantization
constexpr float FP8_INV_SCALE = 1.f / 16.f;

typedef unsigned int uint;
typedef unsigned short ushort;
typedef unsigned char uchar;

using bf16x8 = __attribute__((ext_vector_type(8))) short;   // 4 VGPRs
using f32x4  = __attribute__((ext_vector_type(4))) float;

#if defined(__has_builtin)
#if __has_builtin(__builtin_amdgcn_cvt_pk_f32_fp8) && __has_builtin(__builtin_amdgcn_cvt_pk_fp8_f32)
#define HW_FP8 1
#endif
#endif

static __device__ inline ushort f2bf(float f) {   // round-to-nearest-even bf16
  uint u = __float_as_uint(f);
  return (ushort)((u + 0x7fffu + ((u >> 16) & 1u)) >> 16);
}
static __device__ inline float bf2f(ushort b) {
  return __uint_as_float((uint)b << 16);
}
static __device__ inline uint pack2bf(float a, float b) {
  return (uint)f2bf(a) | ((uint)f2bf(b) << 16);
}

// ---- fp8 e4m3 (OCP) helpers: HW path + fallback ----
static __device__ inline uchar enc_fp8_byte(float f) {
#ifdef HW_FP8
  return (uchar)(__builtin_amdgcn_cvt_pk_fp8_f32(f, f, 0, false) & 0xff);
#else
  float a = fabsf(f);
  uint s = (f < 0.f) ? 0x80u : 0u;
  if (!(a > 0.f)) return (uchar)s;
  a = fminf(a, 448.f);
  uint b = __float_as_uint(a);
  int e = (int)(b >> 23) - 127;
  if (e < -6) {                       // denormal domain: multiples of 2^-9
    int q = (int)rintf(a * 512.f);
    if (q <= 0) return (uchar)s;
    if (q >= 8) return (uchar)(s | 0x08u);
    return (uchar)(s | (uint)q);
  }
  uint r = b + 0x7ffffu + ((b >> 20) & 1u);   // RTN-even at mantissa bit 20
  uint m = (r >> 20) & 7u;
  int ee = (int)(r >> 23) - 127 + 7;
  if (ee <= 0) return (uchar)(s | 0x08u);
  if (ee > 15) return (uchar)(s | 0x7eu);
  return (uchar)(s | ((uint)ee << 3) | m);
#endif
}

static __device__ inline float dec_fp8_byte(uint em_s) {   // fallback scalar decode
  uint s = (em_s & 0x80u) << 24;
  uint em = em_s & 0x7fu;
  float v;
  if (em < 8) v = (float)em * (1.f / 512.f);
  else v = __uint_as_float((em + (120u << 3)) << 20);
  return __uint_as_float(__float_as_uint(v) | s);
}

static __device__ inline void dec_fp8x4(uint u, float* dst) {
#ifdef HW_FP8
  auto a = __builtin_amdgcn_cvt_pk_f32_fp8((int)u, false);
  auto b = __builtin_amdgcn_cvt_pk_f32_fp8((int)u, true);
  dst[0] = a[0]; dst[1] = a[1]; dst[2] = b[0]; dst[3] = b[1];
#else
  dst[0] = dec_fp8_byte(u & 0xffu);
  dst[1] = dec_fp8_byte((u >> 8) & 0xffu);
  dst[2] = dec_fp8_byte((u >> 16) & 0xffu);
  dst[3] = dec_fp8_byte(u >> 24);
#endif
}

// sorted-batch lower_bound: first i with batch[i] >= g
static __device__ inline int lb_batch(const int* __restrict__ batch, int n, int g) {
  int lo = 0, hi = n;
  while (lo < hi) {
    int mid = (lo + hi) >> 1;
    if (batch[mid] < g) lo = mid + 1; else hi = mid;
  }
  return lo;
}

// ---------------- fused: single-pass bucket fill (padded) + weight transposes -------
// blocks [0, fill_grid): distribute (src,dst) into pairs_padded[bucket*BKT_CAP + pos]
// blocks [fill_grid, fill_grid+wt_grid): wt[c][k] = bf16(W[k][c])
__global__ __launch_bounds__(256) void fill_and_convert_kernel(
    const int* __restrict__ src, const int* __restrict__ dst,
    int* __restrict__ bucket_fill_count, uint* __restrict__ pairs,
    int e, int nbk, int fill_grid,
    const float* __restrict__ enc_w1, const float* __restrict__ enc_w2,
    const float* __restrict__ gcn_w,
    ushort* __restrict__ wt_e1, ushort* __restrict__ wt_e2, ushort* __restrict__ wt_g,
    int L) {
  int b = blockIdx.x;
  int t = threadIdx.x;
  if (b < fill_grid) {
    __shared__ int hist[512];
    for (int i = t; i < nbk; i += 256) hist[i] = 0;
    __syncthreads();
    int lo = b * EPB;
    int hi = lo + EPB; if (hi > e) hi = e;
    for (int i = lo + t; i < hi; i += 256) atomicAdd(&hist[dst[i] >> BKT_SHIFT], 1);
    __syncthreads();
    for (int i = t; i < nbk; i += 256) {
      int c = hist[i];
      hist[i] = c ? atomicAdd(&bucket_fill_count[i], c) : 0;   // hist = local write base
    }
    __syncthreads();
    for (int i = lo + t; i < hi; i += 256) {
      int s = src[i], d = dst[i];
      int bkt = d >> BKT_SHIFT;
      int pos = atomicAdd(&hist[bkt], 1);
      pairs[(size_t)bkt * BKT_CAP + pos] = ((uint)s << 8) | (uint)(d & 255);
    }
  } else {
    const int S0 = 128 * FD, S1 = 128 * HD;
    int i = (b - fill_grid) * 256 + t;
    if (i < S0) {
      int c = i / FD, k = i - c * FD;
      wt_e1[i] = f2bf(enc_w1[k * 128 + c]);
    } else if (i < S0 + S1) {
      int j = i - S0;
      int c = j / HD, k = j - c * HD;
      wt_e2[j] = f2bf(enc_w2[k * 128 + c]);
    } else if (i < S0 + S1 + L * S1) {
      int j = i - S0 - S1;
      int l = j / S1, jj = j - l * S1;
      int c = jj / HD, k = jj - c * HD;
      wt_g[(size_t)l * S1 + jj] = f2bf(gcn_w[(size_t)l * HD * HD + k * 128 + c]);
    }
  }
}

// scan bucket_fill_count -> bucket_base (exclusive, +total at [nbk])
__global__ __launch_bounds__(512) void bucket_scan_kernel(const int* __restrict__ bucket_count,
    int* __restrict__ bucket_base, int nbk) {
  __shared__ int sh[512];
  int t = threadIdx.x;
  int v = (t < nbk) ? bucket_count[t] : 0;
  sh[t] = v;
  __syncthreads();
  for (int d = 1; d < 512; d <<= 1) {
    int u = (t >= d) ? sh[t - d] : 0;
    __syncthreads();
    sh[t] += u;
    __syncthreads();
  }
  if (t < nbk) bucket_base[t] = sh[t] - v;
  if (t == 511) bucket_base[nbk] = sh[511];
}

// one block per bucket: count per-node in LDS, scan -> offs & dinv, scatter to
// CONTIGUOUS csr_src at bucket_base (agg layout unchanged).
__global__ __launch_bounds__(256) void bucket_scatter_kernel(const uint* __restrict__ pairs,
    const int* __restrict__ bucket_base, int* __restrict__ offs,
    float* __restrict__ dinv, int* __restrict__ csr_src, int n, int nbk) {
  __shared__ int cnt[256];
  __shared__ int pre[256];
  int b = blockIdx.x, t = threadIdx.x;
  int node0 = b << BKT_SHIFT;
  bool valid_node = (node0 + t) < n;
  cnt[t] = 0;
  __syncthreads();
  int lo = bucket_base[b];
  int ecnt = bucket_base[b + 1] - lo;
  const uint* bp = pairs + (size_t)b * BKT_CAP;
  for (int i = t; i < ecnt; i += 256)
    atomicAdd(&cnt[bp[i] & 255u], 1);
  __syncthreads();
  int v = cnt[t];
  pre[t] = v;
  __syncthreads();
  for (int d = 1; d < 256; d <<= 1) {
    int u = (t >= d) ? pre[t - d] : 0;
    __syncthreads();
    pre[t] += u;
    __syncthreads();
  }
  int off = lo + pre[t] - v;   // exclusive prefix within bucket + bucket base
  if (valid_node) {
    offs[node0 + t] = off;
    dinv[node0 + t] = rsqrtf((float)(v + 1));   // +1: self-loop
  }
  __syncthreads();
  cnt[t] = off;   // reuse as cursor
  __syncthreads();
  for (int i = t; i < ecnt; i += 256) {
    uint pp = bp[i];
    int pos = atomicAdd(&cnt[pp & 255u], 1);
    csr_src[pos] = (int)(pp >> 8);
  }
  if (b == 0 && t == 0) offs[n] = bucket_base[nbk];
}

// ---------------- fused encoder: x = relu(nf@W1+b1)@W2 + b2  (bf16 out) -----------
__global__ __launch_bounds__(256) void encoder_fused_kernel(
    const float* __restrict__ nf, const ushort* __restrict__ wt1,
    const float* __restrict__ b1, const ushort* __restrict__ wt2,
    const float* __restrict__ b2, ushort* __restrict__ xout, int M) {
  __shared__ ushort As[64 * FD];     // 8 KB
  __shared__ ushort W1s[128 * FD];   // 16 KB
  __shared__ ushort Mid[64 * HD];    // 16 KB
  __shared__ ushort W2s[128 * HD];   // 32 KB
  const int tid = threadIdx.x;
  const int r0 = blockIdx.x * 64;

  {
    constexpr int C4 = FD / 4;
    const float4* A4 = (const float4*)nf;
    #pragma unroll
    for (int i = tid; i < 64 * C4; i += 256) {
      int r = i / C4, c4 = i - r * C4;
      int row = r0 + r;
      float4 v = make_float4(0.f, 0.f, 0.f, 0.f);
      if (row < M) v = A4[(size_t)row * C4 + c4];
      ushort4 u;
      u.x = f2bf(v.x); u.y = f2bf(v.y); u.z = f2bf(v.z); u.w = f2bf(v.w);
      int elem = (r * FD + c4 * 4) ^ ((r & 7) << 3);
      *(ushort4*)&As[elem] = u;
    }
  }
  {
    constexpr int C8 = FD / 8;
    const uint4* W4 = (const uint4*)wt1;
    #pragma unroll
    for (int i = tid; i < 128 * C8; i += 256) {
      int c = i / C8, k8 = i - c * C8;
      uint4 v = W4[i];
      int elem = (c * FD + k8 * 8) ^ ((c & 7) << 3);
      *(uint4*)&W1s[elem] = v;
    }
  }
  {
    constexpr int C8 = HD / 8;
    const uint4* W4 = (const uint4*)wt2;
    #pragma unroll
    for (int i = tid; i < 128 * C8; i += 256) {
      int c = i / C8, k8 = i - c * C8;
      uint4 v = W4[i];
      int elem = (c * HD + k8 * 8) ^ ((c & 7) << 3);
      *(uint4*)&W2s[elem] = v;
    }
  }
  __syncthreads();

  const int l = tid & 63;
  const int wid = tid >> 6;
  const int lr = l & 15;
  const int lk = l >> 4;
  const int wr = wid * 16;

  // GEMM1: Mid = relu(A @ W1 + b1), swizzled
  {
    f32x4 acc[8];
    #pragma unroll
    for (int cb = 0; cb < 8; ++cb) acc[cb] = (f32x4){0.f, 0.f, 0.f, 0.f};
    #pragma unroll
    for (int kc = 0; kc < FD / 32; ++kc) {
      int ar = wr + lr;
      bf16x8 af = *(const bf16x8*)&As[(ar * FD + kc * 32 + lk * 8) ^ ((ar & 7) << 3)];
      #pragma unroll
      for (int cb = 0; cb < 8; ++cb) {
        int col = cb * 16 + lr;
        bf16x8 bfr = *(const bf16x8*)&W1s[(col * FD + kc * 32 + lk * 8) ^ ((col & 7) << 3)];
        acc[cb] = __builtin_amdgcn_mfma_f32_16x16x32_bf16(af, bfr, acc[cb], 0, 0, 0);
      }
    }
    #pragma unroll
    for (int cb = 0; cb < 8; ++cb) {
      int col = cb * 16 + lr;
      float bb = b1[col];
      #pragma unroll
      for (int j = 0; j < 4; ++j) {
        int row = wr + lk * 4 + j;
        float o = fmaxf(acc[cb][j] + bb, 0.f);
        Mid[(row * HD + col) ^ ((row & 7) << 3)] = f2bf(o);
      }
    }
  }
  __syncthreads();

  // GEMM2: x = Mid @ W2 + b2
  f32x4 acc[8];
  #pragma unroll
  for (int cb = 0; cb < 8; ++cb) acc[cb] = (f32x4){0.f, 0.f, 0.f, 0.f};
  #pragma unroll
  for (int kc = 0; kc < HD / 32; ++kc) {
    int ar = wr + lr;
    bf16x8 af = *(const bf16x8*)&Mid[(ar * HD + kc * 32 + lk * 8) ^ ((ar & 7) << 3)];
    #pragma unroll
    for (int cb = 0; cb < 8; ++cb) {
      int col = cb * 16 + lr;
      bf16x8 bfr = *(const bf16x8*)&W2s[(col * HD + kc * 32 + lk * 8) ^ ((col & 7) << 3)];
      acc[cb] = __builtin_amdgcn_mfma_f32_16x16x32_bf16(af, bfr, acc[cb], 0, 0, 0);
    }
  }
  __syncthreads();   // all Mid readers done; reuse Mid linear as epilogue buffer
  #pragma unroll
  for (int cb = 0; cb < 8; ++cb) {
    int col = cb * 16 + lr;
    float bb = b2[col];
    #pragma unroll
    for (int j = 0; j < 4; ++j) {
      int row = wr + lk * 4 + j;
      Mid[row * HD + col] = f2bf(acc[cb][j] + bb);
    }
  }
  __syncthreads();
  {
    const uint4* Ms4 = (const uint4*)Mid;
    uint4* O4 = (uint4*)xout;
    #pragma unroll
    for (int k = 0; k < 4; ++k) {
      int i = tid + k * 256;
      int row = i >> 4;
      if (r0 + row < M) O4[((size_t)r0 + row) * 16 + (i & 15)] = Ms4[i];
    }
  }
}

// ---------------- multi-tile MFMA GEMM (GCN layers): fp8 out, dinv*16 folded ------
__global__ __launch_bounds__(256) void mfma_gemm_fp8_kernel(const ushort* __restrict__ A,
    const ushort* __restrict__ Wt, uchar* __restrict__ Cout,
    const float* __restrict__ dinv, int M, int ntiles) {
  __shared__ ushort As[64 * HD];    // 16 KB
  __shared__ ushort Ws[128 * HD];   // 32 KB
  const int tid = threadIdx.x;

  {
    constexpr int C8 = HD / 8;
    const uint4* W4 = (const uint4*)Wt;
    #pragma unroll
    for (int i = tid; i < 128 * C8; i += 256) {
      int c = i / C8, k8 = i - c * C8;
      uint4 v = W4[i];
      int elem = (c * HD + k8 * 8) ^ ((c & 7) << 3);
      *(uint4*)&Ws[elem] = v;
    }
  }

  const int l = tid & 63;
  const int wid = tid >> 6;
  const int lr = l & 15;
  const int lk = l >> 4;
  const int wr = wid * 16;

  for (int tile = blockIdx.x; tile < ntiles; tile += gridDim.x) {
    __syncthreads();
    const int r0 = tile * 64;
    {
      constexpr int C8 = HD / 8;
      const uint4* A4 = (const uint4*)A;
      #pragma unroll
      for (int i = tid; i < 64 * C8; i += 256) {
        int r = i / C8, c8 = i - r * C8;
        int row = r0 + r;
        uint4 v = make_uint4(0u, 0u, 0u, 0u);
        if (row < M) v = A4[(size_t)row * C8 + c8];
        int elem = (r * HD + c8 * 8) ^ ((r & 7) << 3);
        *(uint4*)&As[elem] = v;
      }
    }
    __syncthreads();

    f32x4 acc[8];
    #pragma unroll
    for (int cb = 0; cb < 8; ++cb) acc[cb] = (f32x4){0.f, 0.f, 0.f, 0.f};
    #pragma unroll
    for (int kc = 0; kc < HD / 32; ++kc) {
      int ar = wr + lr;
      bf16x8 af = *(const bf16x8*)&As[(ar * HD + kc * 32 + lk * 8) ^ ((ar & 7) << 3)];
      #pragma unroll
      for (int cb = 0; cb < 8; ++cb) {
        int col = cb * 16 + lr;
        bf16x8 bfr = *(const bf16x8*)&Ws[(col * HD + kc * 32 + lk * 8) ^ ((col & 7) << 3)];
        acc[cb] = __builtin_amdgcn_mfma_f32_16x16x32_bf16(af, bfr, acc[cb], 0, 0, 0);
      }
    }
    __syncthreads();   // all As readers done; reuse As as fp8 epilogue buffer

    uchar* Cs = (uchar*)As;
    float dv[4];
    #pragma unroll
    for (int j = 0; j < 4; ++j) {
      int row = r0 + wr + lk * 4 + j;
      dv[j] = (row < M) ? dinv[row] * FP8_SCALE : 0.f;
    }
    #pragma unroll
    for (int cb = 0; cb < 8; ++cb) {
      int col = cb * 16 + lr;
      #pragma unroll
      for (int j = 0; j < 4; ++j) {
        int row = wr + lk * 4 + j;
        Cs[row * 128 + col] = enc_fp8_byte(acc[cb][j] * dv[j]);
      }
    }
    __syncthreads();
    {
      const uint4* Cs4 = (const uint4*)Cs;
      uint4* O4 = (uint4*)Cout;
      #pragma unroll
      for (int k = 0; k < 2; ++k) {
        int i = tid + k * 256;
        int row = i >> 3;
        if (r0 + row < M) O4[((size_t)r0 + row) * 8 + (i & 7)] = Cs4[i];
      }
    }
  }
}

// ---------------- GCN aggregation + residual update (round-9 layout, unchanged) ----
__global__ __launch_bounds__(256) void agg_update_kernel(
    const uchar* __restrict__ xws, ushort* __restrict__ x,
    const int* __restrict__ csr_src, const int* __restrict__ offs,
    const float* __restrict__ dinv, const float* __restrict__ bias, int n) {
  int node = blockIdx.x * 4 + (threadIdx.x >> 6);
  if (node >= n) return;
  int lane = threadIdx.x & 63;
  int grp = lane >> 4;       // edge group 0..3
  int cl = lane & 15;        // row chunk: dims 8*cl .. 8*cl+7
  const uint2* xw2 = (const uint2*)xws;   // row = 16 uint2 (128 fp8)
  float acc[8];
  #pragma unroll
  for (int k = 0; k < 8; ++k) acc[k] = 0.f;

  auto add_row = [&](uint2 v) {
    float f[4];
    dec_fp8x4(v.x, f);
    acc[0] += f[0]; acc[1] += f[1]; acc[2] += f[2]; acc[3] += f[3];
    dec_fp8x4(v.y, f);
    acc[4] += f[0]; acc[5] += f[1]; acc[6] += f[2]; acc[7] += f[3];
  };

  int beg = offs[node], end = offs[node + 1];
  int j = beg + grp;
  for (; j + 12 < end; j += 16) {
    int s0 = csr_src[j];
    int s1 = csr_src[j + 4];
    int s2 = csr_src[j + 8];
    int s3 = csr_src[j + 12];
    uint2 v0 = xw2[(size_t)s0 * 16 + cl];
    uint2 v1 = xw2[(size_t)s1 * 16 + cl];
    uint2 v2 = xw2[(size_t)s2 * 16 + cl];
    uint2 v3 = xw2[(size_t)s3 * 16 + cl];
    add_row(v0); add_row(v1); add_row(v2); add_row(v3);
  }
  for (; j + 4 < end; j += 8) {
    int s0 = csr_src[j];
    int s1 = csr_src[j + 4];
    uint2 v0 = xw2[(size_t)s0 * 16 + cl];
    uint2 v1 = xw2[(size_t)s1 * 16 + cl];
    add_row(v0); add_row(v1);
  }
  if (j < end) {
    uint2 v0 = xw2[(size_t)csr_src[j] * 16 + cl];
    add_row(v0);
  }
  if (grp == 0) {   // self-loop term
    uint2 vi = xw2[(size_t)node * 16 + cl];
    add_row(vi);
  }
  #pragma unroll
  for (int k = 0; k < 8; ++k) {
    acc[k] += __shfl_xor(acc[k], 16);
    acc[k] += __shfl_xor(acc[k], 32);
  }
  if (grp == 0) {
    float di = dinv[node] * FP8_INV_SCALE;
    const float4* b4 = (const float4*)bias;
    float4 bb0 = b4[cl * 2], bb1 = b4[cl * 2 + 1];
    float bbv[8] = {bb0.x, bb0.y, bb0.z, bb0.w, bb1.x, bb1.y, bb1.z, bb1.w};
    uint4* xv4 = (uint4*)x;
    size_t xi = (size_t)node * 16 + cl;
    uint4 xv = xv4[xi];
    uint xu[4] = {xv.x, xv.y, xv.z, xv.w};
    float o[8];
    #pragma unroll
    for (int q = 0; q < 4; ++q) {
      float lo = __uint_as_float(xu[q] << 16);
      float hi = __uint_as_float(xu[q] & 0xffff0000u);
      o[2 * q]     = fmaxf(fmaf(acc[2 * q],     di, bbv[2 * q]),     0.f) + lo;
      o[2 * q + 1] = fmaxf(fmaf(acc[2 * q + 1], di, bbv[2 * q + 1]), 0.f) + hi;
    }
    uint4 ou;
    ou.x = pack2bf(o[0], o[1]);
    ou.y = pack2bf(o[2], o[3]);
    ou.z = pack2bf(o[4], o[5]);
    ou.w = pack2bf(o[6], o[7]);
    xv4[xi] = ou;
  }
}

// ---------------- per-graph mean/max pooling: partial stage (binary-search bounds) --
__global__ __launch_bounds__(256) void pool_partial_kernel(const ushort* __restrict__ x,
    const int* __restrict__ batch, int n,
    float* __restrict__ psum, float* __restrict__ pmax) {
  __shared__ float ssum[16][128];
  __shared__ float smax[16][128];
  int g = blockIdx.x / PCH, ch = blockIdx.x % PCH;
  int t = threadIdx.x;
  int rg = t >> 4, cg = t & 15;
  int s0 = lb_batch(batch, n, g);
  int s1 = lb_batch(batch, n, g + 1);
  int cnt = s1 - s0;
  int len = (cnt + PCH - 1) / PCH;
  int lo = s0 + ch * len;
  int hi = lo + len; if (hi > s1) hi = s1;
  float sum[8], mx[8];
  #pragma unroll
  for (int k = 0; k < 8; ++k) { sum[k] = 0.f; mx[k] = -INFINITY; }
  const uint4* x4 = (const uint4*)x;
  for (int r = lo + rg; r < hi; r += 16) {
    uint4 v = x4[(size_t)r * 16 + cg];
    uint uu[4] = {v.x, v.y, v.z, v.w};
    #pragma unroll
    for (int q = 0; q < 4; ++q) {
      float a = __uint_as_float(uu[q] << 16);
      float b = __uint_as_float(uu[q] & 0xffff0000u);
      sum[2 * q] += a;     mx[2 * q]     = fmaxf(mx[2 * q], a);
      sum[2 * q + 1] += b; mx[2 * q + 1] = fmaxf(mx[2 * q + 1], b);
    }
  }
  #pragma unroll
  for (int k = 0; k < 8; ++k) {
    ssum[rg][cg * 8 + k] = sum[k];
    smax[rg][cg * 8 + k] = mx[k];
  }
  __syncthreads();
  #pragma unroll
  for (int d = 8; d > 0; d >>= 1) {
    if (rg < d) {
      #pragma unroll
      for (int k = 0; k < 8; ++k) {
        int c = cg * 8 + k;
        ssum[rg][c] += ssum[rg + d][c];
        smax[rg][c] = fmaxf(smax[rg][c], smax[rg + d][c]);
      }
    }
    __syncthreads();
  }
  if (rg == 0) {
    #pragma unroll
    for (int k = 0; k < 8; ++k) {
      int c = cg * 8 + k;
      psum[(size_t)blockIdx.x * HD + c] = ssum[0][c];
      pmax[(size_t)blockIdx.x * HD + c] = smax[0][c];
    }
  }
}

// ---------------- pool-final + decoder + value heads (one block per graph) ----------
__global__ __launch_bounds__(128) void heads_kernel(
    const float* __restrict__ psum, const float* __restrict__ pmax,
    const int* __restrict__ batch, int n,
    const float* __restrict__ dw1, const float* __restrict__ db1,
    const float* __restrict__ dw2, const float* __restrict__ db2,
    const float* __restrict__ dw3, const float* __restrict__ db3,
    const float* __restrict__ vw1, const float* __restrict__ vb1,
    const float* __restrict__ vw2, const float* __restrict__ vb2,
    float* __restrict__ out, int ng) {
  __shared__ float rep[256];
  __shared__ float h1[128];
  __shared__ float h2[64];
  __shared__ float v1[128];
  int g = blockIdx.x, t = threadIdx.x;
  {
    float sum = 0.f, mx = -INFINITY;
    #pragma unroll
    for (int ch = 0; ch < PCH; ++ch) {
      sum += psum[(size_t)(g * PCH + ch) * HD + t];
      mx = fmaxf(mx, pmax[(size_t)(g * PCH + ch) * HD + t]);
    }
    int s0 = lb_batch(batch, n, g);
    int s1 = lb_batch(batch, n, g + 1);
    int cnt = s1 - s0;
    float denom = (float)(cnt > 0 ? cnt : 1);
    rep[t] = sum / denom;
    rep[128 + t] = mx;
  }
  __syncthreads();
  float a = db1[t], b = vb1[t];
  for (int k = 0; k < 256; ++k) {
    float rv = rep[k];
    a = fmaf(rv, dw1[k * 128 + t], a);
    b = fmaf(rv, vw1[k * 128 + t], b);
  }
  h1[t] = fmaxf(a, 0.f);
  v1[t] = fmaxf(b, 0.f);
  __syncthreads();
  if (t < 64) {
    float c = db2[t];
    for (int k = 0; k < 128; ++k) c = fmaf(h1[k], dw2[k * 64 + t], c);
    h2[t] = fmaxf(c, 0.f);
  }
  __syncthreads();
  if (t == 0) {
    float l0 = db3[0], l2 = db3[2];
    for (int k = 0; k < 64; ++k) {
      l0 = fmaf(h2[k], dw3[k * 3 + 0], l0);
      l2 = fmaf(h2[k], dw3[k * 3 + 2], l2);
    }
    out[g] = 1.f / (1.f + expf(-l0));          // adaptation_prob
    out[ng + g] = 1.0f;                        // softmax over 1 element == 1
    out[2 * ng + g] = 1.f / (1.f + expf(-l2)); // urgency_score
    float v = vb2[0];
    for (int k = 0; k < 128; ++k) v = fmaf(v1[k], vw2[k], v);
    out[3 * ng + g] = v;                       // value_estimate
  }
}

// ---------------- launch ----------------
extern "C" void kernel_launch(void* const* d_in, const int* in_sizes, int n_in,
                              void* d_out, int out_size, void* d_ws, size_t ws_size,
                              hipStream_t stream) {
  const float* nf     = (const float*)d_in[0];
  const int*   ei     = (const int*)d_in[1];
  const int*   batch  = (const int*)d_in[2];
  const float* enc_w1 = (const float*)d_in[3];
  const float* enc_b1 = (const float*)d_in[4];
  const float* enc_w2 = (const float*)d_in[5];
  const float* enc_b2 = (const float*)d_in[6];
  const float* gcn_w  = (const float*)d_in[7];
  const float* gcn_b  = (const float*)d_in[8];
  const float* dec_w1 = (const float*)d_in[9];
  const float* dec_b1 = (const float*)d_in[10];
  const float* dec_w2 = (const float*)d_in[11];
  const float* dec_b2 = (const float*)d_in[12];
  const float* dec_w3 = (const float*)d_in[13];
  const float* dec_b3 = (const float*)d_in[14];
  const float* val_w1 = (const float*)d_in[15];
  const float* val_b1 = (const float*)d_in[16];
  const float* val_w2 = (const float*)d_in[17];
  const float* val_b2 = (const float*)d_in[18];
  float* out = (float*)d_out;

  const int n = in_sizes[0] / FD;           // 100000
  const int e = in_sizes[1] / 2;            // 1600000
  const int L = in_sizes[7] / (HD * HD);    // 3
  const int G = out_size / 4;               // 64

  // workspace carve
  char* p = (char*)d_ws;
  auto carve = [&](size_t bytes) {
    void* r = (void*)p;
    p += (bytes + 255) & ~(size_t)255;
    return r;
  };
  const int nbk   = (n + (1 << BKT_SHIFT) - 1) >> BKT_SHIFT;   // 391 buckets
  ushort* x       = (ushort*)carve((size_t)n * HD * 2);        // bf16 x
  uchar*  xw8     = (uchar*)carve((size_t)n * HD);             // fp8 message rows
  uint*   pairs   = (uint*)carve((size_t)nbk * BKT_CAP * 4);   // padded bucket pairs
  float*  dinv    = (float*)carve((size_t)n * 4);
  int*    offs    = (int*)carve((size_t)(n + 1) * 4);
  int*    csr_src = (int*)carve((size_t)e * 4);
  float*  psum    = (float*)carve((size_t)G * PCH * HD * 4);
  float*  pmax    = (float*)carve((size_t)G * PCH * HD * 4);
  int*    bucket_fill_count = (int*)carve((size_t)nbk * 4);
  int*    bucket_base       = (int*)carve((size_t)(nbk + 1) * 4);
  ushort* wt_e1   = (ushort*)carve((size_t)128 * FD * 2);      // enc_w1^T bf16
  ushort* wt_e2   = (ushort*)carve((size_t)128 * HD * 2);      // enc_w2^T bf16
  ushort* wt_g    = (ushort*)carve((size_t)3 * 128 * HD * 2);  // gcn_w^T bf16

  const int ntiles = (n + 63) / 64;
  const int fill_grid = (e + EPB - 1) / EPB;                   // 391
  const int wt_grid = (128 * FD + 128 * HD + L * 128 * HD + 255) / 256;   // 288
  const int gemm_grid = 768;   // 3 blocks/CU, ~2 tiles each

  // ---- graph structure + weight conversion (fused) ----
  hipMemsetAsync(bucket_fill_count, 0, (size_t)nbk * 4, stream);
  fill_and_convert_kernel<<<fill_grid + wt_grid, 256, 0, stream>>>(
      ei, ei + e, bucket_fill_count, pairs, e, nbk, fill_grid,
      enc_w1, enc_w2, gcn_w, wt_e1, wt_e2, wt_g, L);
  bucket_scan_kernel<<<1, 512, 0, stream>>>(bucket_fill_count, bucket_base, nbk);
  bucket_scatter_kernel<<<nbk, 256, 0, stream>>>(pairs, bucket_base, offs, dinv, csr_src, n, nbk);

  // ---- fused encoder ----
  encoder_fused_kernel<<<ntiles, 256, 0, stream>>>(
      nf, wt_e1, enc_b1, wt_e2, enc_b2, x, n);

  // ---- GCN layers: GEMM writes fp8 rows pre-scaled by dinv*16 ----
  for (int l = 0; l < L; ++l) {
    mfma_gemm_fp8_kernel<<<gemm_grid, 256, 0, stream>>>(
        x, wt_g + (size_t)l * 128 * HD, xw8, dinv, n, ntiles);
    agg_update_kernel<<<(n + 3) / 4, 256, 0, stream>>>(
        xw8, x, csr_src, offs, dinv, gcn_b + (size_t)l * HD, n);
  }

  // ---- pooling + heads (bounds via binary search on sorted batch) ----
  pool_partial_kernel<<<G * PCH, 256, 0, stream>>>(x, batch, n, psum, pmax);
  heads_kernel<<<G, 128, 0, stream>>>(psum, pmax, batch, n,
      dec_w1, dec_b1, dec_w2, dec_b2, dec_w3, dec_b3,
      val_w1, val_b1, val_w2, val_b2, out, G);
}

// Round 15
// 314.412 us; speedup vs baseline: 1.2594x; 1.0238x over previous
//
#include <hip/hip_runtime.h>
#include <math.h>

constexpr int HD = 128;   // hidden dim
constexpr int FD = 64;    // input feature dim
constexpr int PCH = 32;   // pooling chunks per graph
constexpr int BKT_SHIFT = 8;           // 256 nodes per bucket
constexpr int BKT_CAP = 6144;          // padded slots per bucket
constexpr int EPB = 4096;              // edges per block in bucket fill
constexpr float FP8_SCALE = 16.f;      // pre-scale before e4m3 quantization
constexpr float FP8_INV_SCALE = 1.f / 16.f;

typedef unsigned int uint;
typedef unsigned short ushort;
typedef unsigned char uchar;

using bf16x8 = __attribute__((ext_vector_type(8))) short;   // 4 VGPRs
using f32x4  = __attribute__((ext_vector_type(4))) float;
using f32x2  = __attribute__((ext_vector_type(2))) float;

#if defined(__has_builtin)
#if __has_builtin(__builtin_amdgcn_cvt_pk_f32_fp8) && __has_builtin(__builtin_amdgcn_cvt_pk_fp8_f32)
#define HW_FP8 1
#endif
#endif

static __device__ inline ushort f2bf(float f) {   // round-to-nearest-even bf16
  uint u = __float_as_uint(f);
  return (ushort)((u + 0x7fffu + ((u >> 16) & 1u)) >> 16);
}
static __device__ inline float bf2f(ushort b) {
  return __uint_as_float((uint)b << 16);
}
static __device__ inline uint pack2bf(float a, float b) {
  return (uint)f2bf(a) | ((uint)f2bf(b) << 16);
}

// ---- fp8 e4m3 (OCP) helpers: HW path + fallback ----
static __device__ inline uchar enc_fp8_byte(float f) {
#ifdef HW_FP8
  return (uchar)(__builtin_amdgcn_cvt_pk_fp8_f32(f, f, 0, false) & 0xff);
#else
  float a = fabsf(f);
  uint s = (f < 0.f) ? 0x80u : 0u;
  if (!(a > 0.f)) return (uchar)s;
  a = fminf(a, 448.f);
  uint b = __float_as_uint(a);
  int e = (int)(b >> 23) - 127;
  if (e < -6) {                       // denormal domain: multiples of 2^-9
    int q = (int)rintf(a * 512.f);
    if (q <= 0) return (uchar)s;
    if (q >= 8) return (uchar)(s | 0x08u);
    return (uchar)(s | (uint)q);
  }
  uint r = b + 0x7ffffu + ((b >> 20) & 1u);   // RTN-even at mantissa bit 20
  uint m = (r >> 20) & 7u;
  int ee = (int)(r >> 23) - 127 + 7;
  if (ee <= 0) return (uchar)(s | 0x08u);
  if (ee > 15) return (uchar)(s | 0x7eu);
  return (uchar)(s | ((uint)ee << 3) | m);
#endif
}

static __device__ inline float dec_fp8_byte(uint em_s) {   // fallback scalar decode
  uint s = (em_s & 0x80u) << 24;
  uint em = em_s & 0x7fu;
  float v;
  if (em < 8) v = (float)em * (1.f / 512.f);
  else v = __uint_as_float((em + (120u << 3)) << 20);
  return __uint_as_float(__float_as_uint(v) | s);
}

// sorted-batch lower_bound: first i with batch[i] >= g
static __device__ inline int lb_batch(const int* __restrict__ batch, int n, int g) {
  int lo = 0, hi = n;
  while (lo < hi) {
    int mid = (lo + hi) >> 1;
    if (batch[mid] < g) lo = mid + 1; else hi = mid;
  }
  return lo;
}

// ---------------- fused: single-pass bucket fill (padded) + weight transposes -------
__global__ __launch_bounds__(256) void fill_and_convert_kernel(
    const int* __restrict__ src, const int* __restrict__ dst,
    int* __restrict__ bucket_fill_count, uint* __restrict__ pairs,
    int e, int nbk, int fill_grid,
    const float* __restrict__ enc_w1, const float* __restrict__ enc_w2,
    const float* __restrict__ gcn_w,
    ushort* __restrict__ wt_e1, ushort* __restrict__ wt_e2, ushort* __restrict__ wt_g,
    int L) {
  int b = blockIdx.x;
  int t = threadIdx.x;
  if (b < fill_grid) {
    __shared__ int hist[512];
    for (int i = t; i < nbk; i += 256) hist[i] = 0;
    __syncthreads();
    int lo = b * EPB;
    int hi = lo + EPB; if (hi > e) hi = e;
    for (int i = lo + t; i < hi; i += 256) atomicAdd(&hist[dst[i] >> BKT_SHIFT], 1);
    __syncthreads();
    for (int i = t; i < nbk; i += 256) {
      int c = hist[i];
      hist[i] = c ? atomicAdd(&bucket_fill_count[i], c) : 0;   // local write base
    }
    __syncthreads();
    for (int i = lo + t; i < hi; i += 256) {
      int s = src[i], d = dst[i];
      int bkt = d >> BKT_SHIFT;
      int pos = atomicAdd(&hist[bkt], 1);
      pairs[(size_t)bkt * BKT_CAP + pos] = ((uint)s << 8) | (uint)(d & 255);
    }
  } else {
    const int S0 = 128 * FD, S1 = 128 * HD;
    int i = (b - fill_grid) * 256 + t;
    if (i < S0) {
      int c = i / FD, k = i - c * FD;
      wt_e1[i] = f2bf(enc_w1[k * 128 + c]);
    } else if (i < S0 + S1) {
      int j = i - S0;
      int c = j / HD, k = j - c * HD;
      wt_e2[j] = f2bf(enc_w2[k * 128 + c]);
    } else if (i < S0 + S1 + L * S1) {
      int j = i - S0 - S1;
      int l = j / S1, jj = j - l * S1;
      int c = jj / HD, k = jj - c * HD;
      wt_g[(size_t)l * S1 + jj] = f2bf(gcn_w[(size_t)l * HD * HD + k * 128 + c]);
    }
  }
}

// scan bucket_fill_count -> bucket_base (exclusive, +total at [nbk])
__global__ __launch_bounds__(512) void bucket_scan_kernel(const int* __restrict__ bucket_count,
    int* __restrict__ bucket_base, int nbk) {
  __shared__ int sh[512];
  int t = threadIdx.x;
  int v = (t < nbk) ? bucket_count[t] : 0;
  sh[t] = v;
  __syncthreads();
  for (int d = 1; d < 512; d <<= 1) {
    int u = (t >= d) ? sh[t - d] : 0;
    __syncthreads();
    sh[t] += u;
    __syncthreads();
  }
  if (t < nbk) bucket_base[t] = sh[t] - v;
  if (t == 511) bucket_base[nbk] = sh[511];
}

// ---------------- merged: bucket scatter (blocks 0..nbk) + fused encoder -----------
// Both depend only on fill+scan; disjoint outputs. One 72KB LDS pool shared.
__global__ __launch_bounds__(256) void scatter_and_encoder_kernel(
    const uint* __restrict__ pairs, const int* __restrict__ bucket_base,
    int* __restrict__ offs, float* __restrict__ dinv, int* __restrict__ csr_src,
    int n, int nbk,
    const float* __restrict__ nf, const ushort* __restrict__ wt1,
    const float* __restrict__ b1, const ushort* __restrict__ wt2,
    const float* __restrict__ b2, ushort* __restrict__ xout, int M) {
  __shared__ uint4 smem4[73728 / 16];   // 72 KB pool
  const int tid = threadIdx.x;

  if (blockIdx.x < (uint)nbk) {
    // ---- bucket scatter (LDS: first 2KB of pool) ----
    int* cnt = (int*)smem4;
    int* pre = cnt + 256;
    int b = blockIdx.x, t = tid;
    int node0 = b << BKT_SHIFT;
    bool valid_node = (node0 + t) < n;
    cnt[t] = 0;
    __syncthreads();
    int lo = bucket_base[b];
    int ecnt = bucket_base[b + 1] - lo;
    const uint* bp = pairs + (size_t)b * BKT_CAP;
    for (int i = t; i < ecnt; i += 256)
      atomicAdd(&cnt[bp[i] & 255u], 1);
    __syncthreads();
    int v = cnt[t];
    pre[t] = v;
    __syncthreads();
    for (int d = 1; d < 256; d <<= 1) {
      int u = (t >= d) ? pre[t - d] : 0;
      __syncthreads();
      pre[t] += u;
      __syncthreads();
    }
    int off = lo + pre[t] - v;
    if (valid_node) {
      offs[node0 + t] = off;
      dinv[node0 + t] = rsqrtf((float)(v + 1));   // +1: self-loop
    }
    __syncthreads();
    cnt[t] = off;   // reuse as cursor
    __syncthreads();
    for (int i = t; i < ecnt; i += 256) {
      uint pp = bp[i];
      int pos = atomicAdd(&cnt[pp & 255u], 1);
      csr_src[pos] = (int)(pp >> 8);
    }
    if (b == 0 && t == 0) offs[n] = bucket_base[nbk];
    return;
  }

  // ---- fused encoder ----
  ushort* As  = (ushort*)smem4;            // 8 KB
  ushort* W1s = As + 64 * FD;              // 16 KB
  ushort* Mid = W1s + 128 * FD;            // 16 KB
  ushort* W2s = Mid + 64 * HD;             // 32 KB
  const int r0 = (blockIdx.x - nbk) * 64;

  {
    constexpr int C4 = FD / 4;
    const float4* A4 = (const float4*)nf;
    #pragma unroll
    for (int i = tid; i < 64 * C4; i += 256) {
      int r = i / C4, c4 = i - r * C4;
      int row = r0 + r;
      float4 v = make_float4(0.f, 0.f, 0.f, 0.f);
      if (row < M) v = A4[(size_t)row * C4 + c4];
      ushort4 u;
      u.x = f2bf(v.x); u.y = f2bf(v.y); u.z = f2bf(v.z); u.w = f2bf(v.w);
      int elem = (r * FD + c4 * 4) ^ ((r & 7) << 3);
      *(ushort4*)&As[elem] = u;
    }
  }
  {
    constexpr int C8 = FD / 8;
    const uint4* W4 = (const uint4*)wt1;
    #pragma unroll
    for (int i = tid; i < 128 * C8; i += 256) {
      int c = i / C8, k8 = i - c * C8;
      uint4 v = W4[i];
      int elem = (c * FD + k8 * 8) ^ ((c & 7) << 3);
      *(uint4*)&W1s[elem] = v;
    }
  }
  {
    constexpr int C8 = HD / 8;
    const uint4* W4 = (const uint4*)wt2;
    #pragma unroll
    for (int i = tid; i < 128 * C8; i += 256) {
      int c = i / C8, k8 = i - c * C8;
      uint4 v = W4[i];
      int elem = (c * HD + k8 * 8) ^ ((c & 7) << 3);
      *(uint4*)&W2s[elem] = v;
    }
  }
  __syncthreads();

  const int l = tid & 63;
  const int wid = tid >> 6;
  const int lr = l & 15;
  const int lk = l >> 4;
  const int wr = wid * 16;

  // GEMM1: Mid = relu(A @ W1 + b1), swizzled
  {
    f32x4 acc[8];
    #pragma unroll
    for (int cb = 0; cb < 8; ++cb) acc[cb] = (f32x4){0.f, 0.f, 0.f, 0.f};
    #pragma unroll
    for (int kc = 0; kc < FD / 32; ++kc) {
      int ar = wr + lr;
      bf16x8 af = *(const bf16x8*)&As[(ar * FD + kc * 32 + lk * 8) ^ ((ar & 7) << 3)];
      #pragma unroll
      for (int cb = 0; cb < 8; ++cb) {
        int col = cb * 16 + lr;
        bf16x8 bfr = *(const bf16x8*)&W1s[(col * FD + kc * 32 + lk * 8) ^ ((col & 7) << 3)];
        acc[cb] = __builtin_amdgcn_mfma_f32_16x16x32_bf16(af, bfr, acc[cb], 0, 0, 0);
      }
    }
    #pragma unroll
    for (int cb = 0; cb < 8; ++cb) {
      int col = cb * 16 + lr;
      float bb = b1[col];
      #pragma unroll
      for (int j = 0; j < 4; ++j) {
        int row = wr + lk * 4 + j;
        float o = fmaxf(acc[cb][j] + bb, 0.f);
        Mid[(row * HD + col) ^ ((row & 7) << 3)] = f2bf(o);
      }
    }
  }
  __syncthreads();

  // GEMM2: x = Mid @ W2 + b2
  f32x4 acc[8];
  #pragma unroll
  for (int cb = 0; cb < 8; ++cb) acc[cb] = (f32x4){0.f, 0.f, 0.f, 0.f};
  #pragma unroll
  for (int kc = 0; kc < HD / 32; ++kc) {
    int ar = wr + lr;
    bf16x8 af = *(const bf16x8*)&Mid[(ar * HD + kc * 32 + lk * 8) ^ ((ar & 7) << 3)];
    #pragma unroll
    for (int cb = 0; cb < 8; ++cb) {
      int col = cb * 16 + lr;
      bf16x8 bfr = *(const bf16x8*)&W2s[(col * HD + kc * 32 + lk * 8) ^ ((col & 7) << 3)];
      acc[cb] = __builtin_amdgcn_mfma_f32_16x16x32_bf16(af, bfr, acc[cb], 0, 0, 0);
    }
  }
  __syncthreads();   // Mid readers done; reuse Mid linear as epilogue buffer
  #pragma unroll
  for (int cb = 0; cb < 8; ++cb) {
    int col = cb * 16 + lr;
    float bb = b2[col];
    #pragma unroll
    for (int j = 0; j < 4; ++j) {
      int row = wr + lk * 4 + j;
      Mid[row * HD + col] = f2bf(acc[cb][j] + bb);
    }
  }
  __syncthreads();
  {
    const uint4* Ms4 = (const uint4*)Mid;
    uint4* O4 = (uint4*)xout;
    #pragma unroll
    for (int k = 0; k < 4; ++k) {
      int i = tid + k * 256;
      int row = i >> 4;
      if (r0 + row < M) O4[((size_t)r0 + row) * 16 + (i & 15)] = Ms4[i];
    }
  }
}

// ---------------- multi-tile MFMA GEMM (GCN layers): fp8 out, dinv*16 folded ------
__global__ __launch_bounds__(256) void mfma_gemm_fp8_kernel(const ushort* __restrict__ A,
    const ushort* __restrict__ Wt, uchar* __restrict__ Cout,
    const float* __restrict__ dinv, int M, int ntiles) {
  __shared__ ushort As[64 * HD];    // 16 KB
  __shared__ ushort Ws[128 * HD];   // 32 KB
  const int tid = threadIdx.x;

  {
    constexpr int C8 = HD / 8;
    const uint4* W4 = (const uint4*)Wt;
    #pragma unroll
    for (int i = tid; i < 128 * C8; i += 256) {
      int c = i / C8, k8 = i - c * C8;
      uint4 v = W4[i];
      int elem = (c * HD + k8 * 8) ^ ((c & 7) << 3);
      *(uint4*)&Ws[elem] = v;
    }
  }

  const int l = tid & 63;
  const int wid = tid >> 6;
  const int lr = l & 15;
  const int lk = l >> 4;
  const int wr = wid * 16;

  for (int tile = blockIdx.x; tile < ntiles; tile += gridDim.x) {
    __syncthreads();
    const int r0 = tile * 64;
    {
      constexpr int C8 = HD / 8;
      const uint4* A4 = (const uint4*)A;
      #pragma unroll
      for (int i = tid; i < 64 * C8; i += 256) {
        int r = i / C8, c8 = i - r * C8;
        int row = r0 + r;
        uint4 v = make_uint4(0u, 0u, 0u, 0u);
        if (row < M) v = A4[(size_t)row * C8 + c8];
        int elem = (r * HD + c8 * 8) ^ ((r & 7) << 3);
        *(uint4*)&As[elem] = v;
      }
    }
    __syncthreads();

    f32x4 acc[8];
    #pragma unroll
    for (int cb = 0; cb < 8; ++cb) acc[cb] = (f32x4){0.f, 0.f, 0.f, 0.f};
    #pragma unroll
    for (int kc = 0; kc < HD / 32; ++kc) {
      int ar = wr + lr;
      bf16x8 af = *(const bf16x8*)&As[(ar * HD + kc * 32 + lk * 8) ^ ((ar & 7) << 3)];
      #pragma unroll
      for (int cb = 0; cb < 8; ++cb) {
        int col = cb * 16 + lr;
        bf16x8 bfr = *(const bf16x8*)&Ws[(col * HD + kc * 32 + lk * 8) ^ ((col & 7) << 3)];
        acc[cb] = __builtin_amdgcn_mfma_f32_16x16x32_bf16(af, bfr, acc[cb], 0, 0, 0);
      }
    }
    __syncthreads();   // As readers done; reuse As as fp8 epilogue buffer

    uchar* Cs = (uchar*)As;
    float dv[4];
    #pragma unroll
    for (int j = 0; j < 4; ++j) {
      int row = r0 + wr + lk * 4 + j;
      dv[j] = (row < M) ? dinv[row] * FP8_SCALE : 0.f;
    }
    #pragma unroll
    for (int cb = 0; cb < 8; ++cb) {
      int col = cb * 16 + lr;
      #pragma unroll
      for (int j = 0; j < 4; ++j) {
        int row = wr + lk * 4 + j;
        Cs[row * 128 + col] = enc_fp8_byte(acc[cb][j] * dv[j]);
      }
    }
    __syncthreads();
    {
      const uint4* Cs4 = (const uint4*)Cs;
      uint4* O4 = (uint4*)Cout;
      #pragma unroll
      for (int k = 0; k < 2; ++k) {
        int i = tid + k * 256;
        int row = i >> 3;
        if (r0 + row < M) O4[((size_t)r0 + row) * 8 + (i & 7)] = Cs4[i];
      }
    }
  }
}

// ---------------- GCN aggregation + residual update ----------------
// Round-9 layout; accumulate via f32x2 vector adds (v_pk_add_f32 hint).
__global__ __launch_bounds__(256) void agg_update_kernel(
    const uchar* __restrict__ xws, ushort* __restrict__ x,
    const int* __restrict__ csr_src, const int* __restrict__ offs,
    const float* __restrict__ dinv, const float* __restrict__ bias, int n) {
  int node = blockIdx.x * 4 + (threadIdx.x >> 6);
  if (node >= n) return;
  int lane = threadIdx.x & 63;
  int grp = lane >> 4;       // edge group 0..3
  int cl = lane & 15;        // row chunk: dims 8*cl .. 8*cl+7
  const uint2* xw2 = (const uint2*)xws;   // row = 16 uint2 (128 fp8)

#ifdef HW_FP8
  f32x2 acc2[4];
  #pragma unroll
  for (int k = 0; k < 4; ++k) acc2[k] = (f32x2){0.f, 0.f};
  auto add_row = [&](uint2 v) {
    acc2[0] += __builtin_amdgcn_cvt_pk_f32_fp8((int)v.x, false);
    acc2[1] += __builtin_amdgcn_cvt_pk_f32_fp8((int)v.x, true);
    acc2[2] += __builtin_amdgcn_cvt_pk_f32_fp8((int)v.y, false);
    acc2[3] += __builtin_amdgcn_cvt_pk_f32_fp8((int)v.y, true);
  };
#else
  float accs[8];
  #pragma unroll
  for (int k = 0; k < 8; ++k) accs[k] = 0.f;
  auto add_row = [&](uint2 v) {
    accs[0] += dec_fp8_byte(v.x & 0xffu);
    accs[1] += dec_fp8_byte((v.x >> 8) & 0xffu);
    accs[2] += dec_fp8_byte((v.x >> 16) & 0xffu);
    accs[3] += dec_fp8_byte(v.x >> 24);
    accs[4] += dec_fp8_byte(v.y & 0xffu);
    accs[5] += dec_fp8_byte((v.y >> 8) & 0xffu);
    accs[6] += dec_fp8_byte((v.y >> 16) & 0xffu);
    accs[7] += dec_fp8_byte(v.y >> 24);
  };
#endif

  int beg = offs[node], end = offs[node + 1];
  int j = beg + grp;
  for (; j + 12 < end; j += 16) {
    int s0 = csr_src[j];
    int s1 = csr_src[j + 4];
    int s2 = csr_src[j + 8];
    int s3 = csr_src[j + 12];
    uint2 v0 = xw2[(size_t)s0 * 16 + cl];
    uint2 v1 = xw2[(size_t)s1 * 16 + cl];
    uint2 v2 = xw2[(size_t)s2 * 16 + cl];
    uint2 v3 = xw2[(size_t)s3 * 16 + cl];
    add_row(v0); add_row(v1); add_row(v2); add_row(v3);
  }
  for (; j + 4 < end; j += 8) {
    int s0 = csr_src[j];
    int s1 = csr_src[j + 4];
    uint2 v0 = xw2[(size_t)s0 * 16 + cl];
    uint2 v1 = xw2[(size_t)s1 * 16 + cl];
    add_row(v0); add_row(v1);
  }
  if (j < end) {
    uint2 v0 = xw2[(size_t)csr_src[j] * 16 + cl];
    add_row(v0);
  }
  if (grp == 0) {   // self-loop term
    uint2 vi = xw2[(size_t)node * 16 + cl];
    add_row(vi);
  }

  float acc[8];
#ifdef HW_FP8
  #pragma unroll
  for (int k = 0; k < 4; ++k) { acc[2 * k] = acc2[k][0]; acc[2 * k + 1] = acc2[k][1]; }
#else
  #pragma unroll
  for (int k = 0; k < 8; ++k) acc[k] = accs[k];
#endif

  #pragma unroll
  for (int k = 0; k < 8; ++k) {
    acc[k] += __shfl_xor(acc[k], 16);
    acc[k] += __shfl_xor(acc[k], 32);
  }
  if (grp == 0) {
    float di = dinv[node] * FP8_INV_SCALE;
    const float4* b4 = (const float4*)bias;
    float4 bb0 = b4[cl * 2], bb1 = b4[cl * 2 + 1];
    float bbv[8] = {bb0.x, bb0.y, bb0.z, bb0.w, bb1.x, bb1.y, bb1.z, bb1.w};
    uint4* xv4 = (uint4*)x;
    size_t xi = (size_t)node * 16 + cl;
    uint4 xv = xv4[xi];
    uint xu[4] = {xv.x, xv.y, xv.z, xv.w};
    float o[8];
    #pragma unroll
    for (int q = 0; q < 4; ++q) {
      float lo = __uint_as_float(xu[q] << 16);
      float hi = __uint_as_float(xu[q] & 0xffff0000u);
      o[2 * q]     = fmaxf(fmaf(acc[2 * q],     di, bbv[2 * q]),     0.f) + lo;
      o[2 * q + 1] = fmaxf(fmaf(acc[2 * q + 1], di, bbv[2 * q + 1]), 0.f) + hi;
    }
    uint4 ou;
    ou.x = pack2bf(o[0], o[1]);
    ou.y = pack2bf(o[2], o[3]);
    ou.z = pack2bf(o[4], o[5]);
    ou.w = pack2bf(o[6], o[7]);
    xv4[xi] = ou;
  }
}

// ---------------- per-graph mean/max pooling: partial stage (binary-search bounds) --
__global__ __launch_bounds__(256) void pool_partial_kernel(const ushort* __restrict__ x,
    const int* __restrict__ batch, int n,
    float* __restrict__ psum, float* __restrict__ pmax) {
  __shared__ float ssum[16][128];
  __shared__ float smax[16][128];
  int g = blockIdx.x / PCH, ch = blockIdx.x % PCH;
  int t = threadIdx.x;
  int rg = t >> 4, cg = t & 15;
  int s0 = lb_batch(batch, n, g);
  int s1 = lb_batch(batch, n, g + 1);
  int cnt = s1 - s0;
  int len = (cnt + PCH - 1) / PCH;
  int lo = s0 + ch * len;
  int hi = lo + len; if (hi > s1) hi = s1;
  float sum[8], mx[8];
  #pragma unroll
  for (int k = 0; k < 8; ++k) { sum[k] = 0.f; mx[k] = -INFINITY; }
  const uint4* x4 = (const uint4*)x;
  for (int r = lo + rg; r < hi; r += 16) {
    uint4 v = x4[(size_t)r * 16 + cg];
    uint uu[4] = {v.x, v.y, v.z, v.w};
    #pragma unroll
    for (int q = 0; q < 4; ++q) {
      float a = __uint_as_float(uu[q] << 16);
      float b = __uint_as_float(uu[q] & 0xffff0000u);
      sum[2 * q] += a;     mx[2 * q]     = fmaxf(mx[2 * q], a);
      sum[2 * q + 1] += b; mx[2 * q + 1] = fmaxf(mx[2 * q + 1], b);
    }
  }
  #pragma unroll
  for (int k = 0; k < 8; ++k) {
    ssum[rg][cg * 8 + k] = sum[k];
    smax[rg][cg * 8 + k] = mx[k];
  }
  __syncthreads();
  #pragma unroll
  for (int d = 8; d > 0; d >>= 1) {
    if (rg < d) {
      #pragma unroll
      for (int k = 0; k < 8; ++k) {
        int c = cg * 8 + k;
        ssum[rg][c] += ssum[rg + d][c];
        smax[rg][c] = fmaxf(smax[rg][c], smax[rg + d][c]);
      }
    }
    __syncthreads();
  }
  if (rg == 0) {
    #pragma unroll
    for (int k = 0; k < 8; ++k) {
      int c = cg * 8 + k;
      psum[(size_t)blockIdx.x * HD + c] = ssum[0][c];
      pmax[(size_t)blockIdx.x * HD + c] = smax[0][c];
    }
  }
}

// ---------------- pool-final + decoder + value heads (one block per graph) ----------
__global__ __launch_bounds__(128) void heads_kernel(
    const float* __restrict__ psum, const float* __restrict__ pmax,
    const int* __restrict__ batch, int n,
    const float* __restrict__ dw1, const float* __restrict__ db1,
    const float* __restrict__ dw2, const float* __restrict__ db2,
    const float* __restrict__ dw3, const float* __restrict__ db3,
    const float* __restrict__ vw1, const float* __restrict__ vb1,
    const float* __restrict__ vw2, const float* __restrict__ vb2,
    float* __restrict__ out, int ng) {
  __shared__ float rep[256];
  __shared__ float h1[128];
  __shared__ float h2[64];
  __shared__ float v1[128];
  int g = blockIdx.x, t = threadIdx.x;
  {
    float sum = 0.f, mx = -INFINITY;
    #pragma unroll
    for (int ch = 0; ch < PCH; ++ch) {
      sum += psum[(size_t)(g * PCH + ch) * HD + t];
      mx = fmaxf(mx, pmax[(size_t)(g * PCH + ch) * HD + t]);
    }
    int s0 = lb_batch(batch, n, g);
    int s1 = lb_batch(batch, n, g + 1);
    int cnt = s1 - s0;
    float denom = (float)(cnt > 0 ? cnt : 1);
    rep[t] = sum / denom;
    rep[128 + t] = mx;
  }
  __syncthreads();
  float a = db1[t], b = vb1[t];
  for (int k = 0; k < 256; ++k) {
    float rv = rep[k];
    a = fmaf(rv, dw1[k * 128 + t], a);
    b = fmaf(rv, vw1[k * 128 + t], b);
  }
  h1[t] = fmaxf(a, 0.f);
  v1[t] = fmaxf(b, 0.f);
  __syncthreads();
  if (t < 64) {
    float c = db2[t];
    for (int k = 0; k < 128; ++k) c = fmaf(h1[k], dw2[k * 64 + t], c);
    h2[t] = fmaxf(c, 0.f);
  }
  __syncthreads();
  if (t == 0) {
    float l0 = db3[0], l2 = db3[2];
    for (int k = 0; k < 64; ++k) {
      l0 = fmaf(h2[k], dw3[k * 3 + 0], l0);
      l2 = fmaf(h2[k], dw3[k * 3 + 2], l2);
    }
    out[g] = 1.f / (1.f + expf(-l0));          // adaptation_prob
    out[ng + g] = 1.0f;                        // softmax over 1 element == 1
    out[2 * ng + g] = 1.f / (1.f + expf(-l2)); // urgency_score
    float v = vb2[0];
    for (int k = 0; k < 128; ++k) v = fmaf(v1[k], vw2[k], v);
    out[3 * ng + g] = v;                       // value_estimate
  }
}

// ---------------- launch ----------------
extern "C" void kernel_launch(void* const* d_in, const int* in_sizes, int n_in,
                              void* d_out, int out_size, void* d_ws, size_t ws_size,
                              hipStream_t stream) {
  const float* nf     = (const float*)d_in[0];
  const int*   ei     = (const int*)d_in[1];
  const int*   batch  = (const int*)d_in[2];
  const float* enc_w1 = (const float*)d_in[3];
  const float* enc_b1 = (const float*)d_in[4];
  const float* enc_w2 = (const float*)d_in[5];
  const float* enc_b2 = (const float*)d_in[6];
  const float* gcn_w  = (const float*)d_in[7];
  const float* gcn_b  = (const float*)d_in[8];
  const float* dec_w1 = (const float*)d_in[9];
  const float* dec_b1 = (const float*)d_in[10];
  const float* dec_w2 = (const float*)d_in[11];
  const float* dec_b2 = (const float*)d_in[12];
  const float* dec_w3 = (const float*)d_in[13];
  const float* dec_b3 = (const float*)d_in[14];
  const float* val_w1 = (const float*)d_in[15];
  const float* val_b1 = (const float*)d_in[16];
  const float* val_w2 = (const float*)d_in[17];
  const float* val_b2 = (const float*)d_in[18];
  float* out = (float*)d_out;

  const int n = in_sizes[0] / FD;           // 100000
  const int e = in_sizes[1] / 2;            // 1600000
  const int L = in_sizes[7] / (HD * HD);    // 3
  const int G = out_size / 4;               // 64

  // workspace carve
  char* p = (char*)d_ws;
  auto carve = [&](size_t bytes) {
    void* r = (void*)p;
    p += (bytes + 255) & ~(size_t)255;
    return r;
  };
  const int nbk   = (n + (1 << BKT_SHIFT) - 1) >> BKT_SHIFT;   // 391 buckets
  ushort* x       = (ushort*)carve((size_t)n * HD * 2);        // bf16 x
  uchar*  xw8     = (uchar*)carve((size_t)n * HD);             // fp8 message rows
  uint*   pairs   = (uint*)carve((size_t)nbk * BKT_CAP * 4);   // padded bucket pairs
  float*  dinv    = (float*)carve((size_t)n * 4);
  int*    offs    = (int*)carve((size_t)(n + 1) * 4);
  int*    csr_src = (int*)carve((size_t)e * 4);
  float*  psum    = (float*)carve((size_t)G * PCH * HD * 4);
  float*  pmax    = (float*)carve((size_t)G * PCH * HD * 4);
  int*    bucket_fill_count = (int*)carve((size_t)nbk * 4);
  int*    bucket_base       = (int*)carve((size_t)(nbk + 1) * 4);
  ushort* wt_e1   = (ushort*)carve((size_t)128 * FD * 2);      // enc_w1^T bf16
  ushort* wt_e2   = (ushort*)carve((size_t)128 * HD * 2);      // enc_w2^T bf16
  ushort* wt_g    = (ushort*)carve((size_t)3 * 128 * HD * 2);  // gcn_w^T bf16

  const int ntiles = (n + 63) / 64;
  const int fill_grid = (e + EPB - 1) / EPB;                   // 391
  const int wt_grid = (128 * FD + 128 * HD + L * 128 * HD + 255) / 256;   // 288
  const int gemm_grid = 768;   // 3 blocks/CU, ~2 tiles each

  // ---- graph structure + weight conversion (fused) ----
  hipMemsetAsync(bucket_fill_count, 0, (size_t)nbk * 4, stream);
  fill_and_convert_kernel<<<fill_grid + wt_grid, 256, 0, stream>>>(
      ei, ei + e, bucket_fill_count, pairs, e, nbk, fill_grid,
      enc_w1, enc_w2, gcn_w, wt_e1, wt_e2, wt_g, L);
  bucket_scan_kernel<<<1, 512, 0, stream>>>(bucket_fill_count, bucket_base, nbk);

  // ---- merged: bucket scatter + fused encoder ----
  scatter_and_encoder_kernel<<<nbk + ntiles, 256, 0, stream>>>(
      pairs, bucket_base, offs, dinv, csr_src, n, nbk,
      nf, wt_e1, enc_b1, wt_e2, enc_b2, x, n);

  // ---- GCN layers: GEMM writes fp8 rows pre-scaled by dinv*16 ----
  for (int l = 0; l < L; ++l) {
    mfma_gemm_fp8_kernel<<<gemm_grid, 256, 0, stream>>>(
        x, wt_g + (size_t)l * 128 * HD, xw8, dinv, n, ntiles);
    agg_update_kernel<<<(n + 3) / 4, 256, 0, stream>>>(
        xw8, x, csr_src, offs, dinv, gcn_b + (size_t)l * HD, n);
  }

  // ---- pooling + heads (bounds via binary search on sorted batch) ----
  pool_partial_kernel<<<G * PCH, 256, 0, stream>>>(x, batch, n, psum, pmax);
  heads_kernel<<<G, 128, 0, stream>>>(psum, pmax, batch, n,
      dec_w1, dec_b1, dec_w2, dec_b2, dec_w3, dec_b3,
      val_w1, val_b1, val_w2, val_b2, out, G);
}